// Round 1
// baseline (906.552 us; speedup 1.0000x reference)
//
#include <hip/hip_runtime.h>
#include <stdint.h>

// ---------------------------------------------------------------------------
// Problem constants (fixed by setup_inputs)
// b=32, n=1024, dim=512, ic=512, cc=256, nh=8, ag=49, hd=64, H=W=c_H=c_W=32
// ---------------------------------------------------------------------------

typedef __attribute__((ext_vector_type(8)))  short          bf16x8;
typedef __attribute__((ext_vector_type(4)))  float          f32x4;
typedef __attribute__((ext_vector_type(4)))  unsigned short u16x4;

__device__ __forceinline__ float bf2f(unsigned short u) {
    union { unsigned int i; float f; } x; x.i = ((unsigned int)u) << 16; return x.f;
}
__device__ __forceinline__ unsigned short f2bf(float f) {
    union { float f; unsigned int i; } x; x.f = f;
    unsigned int i = x.i;
    i += 0x7FFFu + ((i >> 16) & 1u);   // RNE
    return (unsigned short)(i >> 16);
}

// ---------------------------------------------------------------------------
// Elementwise converters
// ---------------------------------------------------------------------------
__global__ void cvt_f32_bf16_kernel(const float* __restrict__ src,
                                    unsigned short* __restrict__ dst) {
    const int i = (blockIdx.x * 256 + threadIdx.x) * 4;
    const f32x4 v = *(const f32x4*)(src + i);
    u16x4 o; o[0]=f2bf(v[0]); o[1]=f2bf(v[1]); o[2]=f2bf(v[2]); o[3]=f2bf(v[3]);
    *(u16x4*)(dst + i) = o;
}

// Wqkv_t[nn][kk] (bf16, N=1536, K=512) from Wq (512,512) and Wkv (512,1024)
__global__ void build_wqkvt_kernel(const float* __restrict__ Wq,
                                   const float* __restrict__ Wkv,
                                   unsigned short* __restrict__ out) {
    const int idx = blockIdx.x * 256 + threadIdx.x;   // = nn*512 + kk
    if (idx >= 1536*512) return;
    const int nn = idx >> 9, kk = idx & 511;
    float v = (nn < 512) ? Wq[kk*512 + nn] : Wkv[kk*1024 + (nn - 512)];
    out[idx] = f2bf(v);
}

__global__ void build_projwt_kernel(const float* __restrict__ W,
                                    unsigned short* __restrict__ out) {
    const int idx = blockIdx.x * 256 + threadIdx.x;   // = nn*512 + kk
    if (idx >= 512*512) return;
    const int nn = idx >> 9, kk = idx & 511;
    out[idx] = f2bf(W[kk*512 + nn]);
}

// ---------------------------------------------------------------------------
// Bias precompute: bilinear 7->32 resize (jax.image.resize semantics:
// half-pixel centers, triangle kernel, edge weights renormalized == clamp)
// bias1[h][a][y*32+x] = resize(an_bias)[h,a,y,x] + ah[h,a,y] + aw[h,a,x]
// bias2[h][y*32+x][a] = resize(na_bias)[h,a,y,x] + ha[h,y,a] + wa[h,x,a]
// ---------------------------------------------------------------------------
__device__ __forceinline__ void bilin_coef(int i, int& i0, int& i1, float& f) {
    float pos = (i + 0.5f) * (7.0f / 32.0f) - 0.5f;
    float fl = floorf(pos);
    i0 = (int)fl; f = pos - fl;
    if (i0 < 0)       { i0 = 0; i1 = 0; f = 0.f; }
    else if (i0 >= 6) { i0 = 6; i1 = 6; f = 0.f; }
    else              { i1 = i0 + 1; }
}
__device__ __forceinline__ float bilin7(const float* __restrict__ s, int y, int x) {
    int y0,y1,x0,x1; float fy,fx;
    bilin_coef(y, y0, y1, fy); bilin_coef(x, x0, x1, fx);
    return (1.f-fy)*((1.f-fx)*s[y0*7+x0] + fx*s[y0*7+x1])
         +      fy *((1.f-fx)*s[y1*7+x0] + fx*s[y1*7+x1]);
}

__global__ void bias_prep_kernel(const float* __restrict__ an, const float* __restrict__ na,
                                 const float* __restrict__ ah, const float* __restrict__ aw,
                                 const float* __restrict__ ha, const float* __restrict__ wa,
                                 float* __restrict__ bias1, float* __restrict__ bias2) {
    int idx = blockIdx.x * 256 + threadIdx.x;
    if (idx < 8*49*1024) {
        const int nn = idx & 1023;
        const int a  = (idx >> 10) % 49;
        const int h  = idx / (49*1024);
        const int y = nn >> 5, x = nn & 31;
        float v = bilin7(an + (h*49 + a)*49, y, x)
                + ah[(h*49 + a)*32 + y] + aw[(h*49 + a)*32 + x];
        bias1[idx] = v;
    } else {
        idx -= 8*49*1024;
        if (idx >= 8*1024*49) return;
        const int a  = idx % 49;
        const int nn = (idx / 49) & 1023;
        const int h  = idx / (49*1024);
        const int y = nn >> 5, x = nn & 31;
        float v = bilin7(na + (h*49 + a)*49, y, x)
                + ha[h*1568 + y*49 + a] + wa[h*1568 + x*49 + a];
        bias2[idx] = v;
    }
}

// ---------------------------------------------------------------------------
// Adaptive avg-pool 32x32 -> 7x7 of q (from bf16 qkv cols 0..511) and context.
// pooled flat layout per batch: index a*768 + c  (this IS the reference's raw
// reshape (b,49,768)->(b,768,7,7); conv reads it as flat[ci*49 + p*7 + q]).
// ---------------------------------------------------------------------------
__global__ void pool_kernel(const unsigned short* __restrict__ qkv,
                            const float* __restrict__ context,
                            float* __restrict__ pooled) {
    const int idx = blockIdx.x * 256 + threadIdx.x;   // b*37632 + a*768 + c
    if (idx >= 32*49*768) return;
    const int c = idx % 768;
    const int a = (idx / 768) % 49;
    const int b = idx / (768*49);
    const int p = a / 7, q = a % 7;
    const int ys = p*32/7, ye = (p*32 + 38)/7;   // ceil((p+1)*32/7)
    const int xs = q*32/7, xe = (q*32 + 38)/7;
    float s = 0.f;
    if (c < 512) {
        for (int y = ys; y < ye; ++y)
            for (int x = xs; x < xe; ++x)
                s += bf2f(qkv[(size_t)(b*1024 + y*32 + x)*1536 + c]);
    } else {
        for (int y = ys; y < ye; ++y)
            for (int x = xs; x < xe; ++x)
                s += context[(size_t)(b*1024 + y*32 + x)*256 + (c - 512)];
    }
    pooled[idx] = s / (float)((ye - ys)*(xe - xs));
}

// im2col for the 3x3 pad-1 conv on the scrambled (768,7,7) view.
// out[(b*49 + p*7+q)*6912 + ci*9 + dy*3 + dx]
__global__ void im2col_kernel(const float* __restrict__ pooled,
                              unsigned short* __restrict__ i2c) {
    const int idx = blockIdx.x * 256 + threadIdx.x;
    if (idx >= 1568*6912) return;
    const int kk = idx % 6912;
    const int m  = idx / 6912;
    const int b = m / 49, spq = m % 49;
    const int p = spq / 7, q = spq % 7;
    const int ci = kk / 9, r = kk % 9;
    const int dy = r / 3, dx = r % 3;
    const int yy = p + dy - 1, xx = q + dx - 1;
    float v = 0.f;
    if (yy >= 0 && yy < 7 && xx >= 0 && xx < 7)
        v = pooled[b*37632 + ci*49 + yy*7 + xx];
    i2c[idx] = f2bf(v);
}

// ---------------------------------------------------------------------------
// NT bf16 MFMA GEMM: C[M,N] = A[M,K] @ Bt[N,K]^T   (m97 structure)
// 128x128 tile, BK=64, 256 thr (2x2 waves, 64x64/wave, 4x4 of 16x16x32 MFMA),
// global_load_lds width 16, XOR-swizzled LDS (16B units: u' = u ^ (row&7)).
// MODE 0: f32 C row-major + bias      (proj -> d_out)
// MODE 1: bf16 C row-major            (qkv)
// MODE 2: f32 scatter to a_t layout [b*25088 + n*49 + s] + bias, mask m<1568
// ---------------------------------------------------------------------------
template <int MODE>
__launch_bounds__(256)
__global__ void gemm_nt(const unsigned short* __restrict__ A,
                        const unsigned short* __restrict__ Bt,
                        void* __restrict__ C,
                        const float* __restrict__ bias,
                        int K, int ldc) {
    __shared__ unsigned short As[128*64];
    __shared__ unsigned short Bs[128*64];
    const int tid  = threadIdx.x;
    const int wid  = tid >> 6;
    const int lane = tid & 63;
    const int m0 = blockIdx.y * 128;
    const int n0 = blockIdx.x * 128;
    const int wm = (wid >> 1) * 64;
    const int wn = (wid & 1) * 64;
    const int lrow = lane & 15;
    const int quad = lane >> 4;
    const int srow = lane >> 3;                  // 0..7 row-in-chunk
    const int scol = ((lane & 7) ^ srow) * 8;    // swizzled source col (bf16 units)

    f32x4 acc[4][4];
#pragma unroll
    for (int i = 0; i < 4; ++i)
#pragma unroll
        for (int j = 0; j < 4; ++j) acc[i][j] = (f32x4){0.f,0.f,0.f,0.f};

    for (int k0 = 0; k0 < K; k0 += 64) {
        __syncthreads();
#pragma unroll
        for (int i = 0; i < 4; ++i) {
            const int chunk = wid*4 + i;
            const int row = chunk*8 + srow;
            __builtin_amdgcn_global_load_lds(
                (const __attribute__((address_space(1))) void*)(A + (size_t)(m0 + row)*K + k0 + scol),
                (__attribute__((address_space(3))) void*)(As + chunk*512), 16, 0, 0);
            __builtin_amdgcn_global_load_lds(
                (const __attribute__((address_space(1))) void*)(Bt + (size_t)(n0 + row)*K + k0 + scol),
                (__attribute__((address_space(3))) void*)(Bs + chunk*512), 16, 0, 0);
        }
        __syncthreads();
#pragma unroll
        for (int kk = 0; kk < 2; ++kk) {
            bf16x8 af[4], bfr[4];
#pragma unroll
            for (int mt = 0; mt < 4; ++mt) {
                const int row = wm + mt*16 + lrow;
                const int u = (kk*4 + quad) ^ (row & 7);
                af[mt] = *(const bf16x8*)(As + row*64 + u*8);
            }
#pragma unroll
            for (int nt = 0; nt < 4; ++nt) {
                const int row = wn + nt*16 + lrow;
                const int u = (kk*4 + quad) ^ (row & 7);
                bfr[nt] = *(const bf16x8*)(Bs + row*64 + u*8);
            }
#pragma unroll
            for (int mt = 0; mt < 4; ++mt)
#pragma unroll
                for (int nt = 0; nt < 4; ++nt)
                    acc[mt][nt] = __builtin_amdgcn_mfma_f32_16x16x32_bf16(
                        af[mt], bfr[nt], acc[mt][nt], 0, 0, 0);
        }
    }
    // epilogue: C/D layout col=lane&15, row=quad*4+r
#pragma unroll
    for (int mt = 0; mt < 4; ++mt) {
#pragma unroll
        for (int nt = 0; nt < 4; ++nt) {
#pragma unroll
            for (int r = 0; r < 4; ++r) {
                const int m = m0 + wm + mt*16 + quad*4 + r;
                const int n = n0 + wn + nt*16 + lrow;
                const float v = acc[mt][nt][r];
                if (MODE == 0) {
                    ((float*)C)[(size_t)m*ldc + n] = v + bias[n];
                } else if (MODE == 1) {
                    ((unsigned short*)C)[(size_t)m*ldc + n] = f2bf(v);
                } else {
                    if (m < 1568) {
                        const int bb = m / 49, ss = m % 49;
                        ((float*)C)[bb*25088 + n*49 + ss] = v + bias[n];
                    }
                }
            }
        }
    }
}

// ---------------------------------------------------------------------------
// Agent attention: agent_v[b,h,a,:] = softmax_j(0.125*a_t.k_j + bias1) @ v
// Block per (b,h), 512 thr (8 waves). k/v tiles (64 j x 64 d) staged in LDS
// (XOR-swizzled 16B units) and read once per wave; each wave owns agents
// a = g*8+wid (g<7). No max-subtraction (|logit| < ~1).
// ---------------------------------------------------------------------------
__launch_bounds__(512)
__global__ void agent_attn_kernel(const unsigned short* __restrict__ qkv,
                                  const float* __restrict__ at_buf,
                                  const float* __restrict__ bias1,
                                  float* __restrict__ agent_v) {
    const int b = blockIdx.x >> 3, h = blockIdx.x & 7;
    __shared__ float at_s[56*64];
    __shared__ float e_s [56*64];
    __shared__ float kt  [64*64];
    __shared__ float vt  [64*64];
    const int tid = threadIdx.x;
    const int wid = tid >> 6, lane = tid & 63;

    for (int i = tid; i < 56*64; i += 512) {
        const int a = i >> 6;
        at_s[i] = (a < 49) ? at_buf[b*25088 + (a*8 + h)*64 + (i & 63)] : 0.f;
    }
    float num[7] = {0,0,0,0,0,0,0};
    float den[7] = {0,0,0,0,0,0,0};
    const int sj = tid >> 3;          // staging row 0..63
    const int su = (tid & 7) * 2;     // staging unit pair

    for (int jt = 0; jt < 16; ++jt) {
        __syncthreads();
        { // stage k & v tiles (bf16 -> f32, swizzled units)
            const unsigned short* kp = qkv + (size_t)(b*1024 + jt*64 + sj)*1536 + 512 + h*64 + su*4;
            const unsigned short* vp = kp + 512;
            u16x4 ka = *(const u16x4*)kp, kb = *(const u16x4*)(kp + 4);
            u16x4 va = *(const u16x4*)vp, vb = *(const u16x4*)(vp + 4);
            const int u0 = su ^ (sj & 15), u1 = (su + 1) ^ (sj & 15);
            f32x4 t;
            t[0]=bf2f(ka[0]); t[1]=bf2f(ka[1]); t[2]=bf2f(ka[2]); t[3]=bf2f(ka[3]);
            *(f32x4*)&kt[sj*64 + u0*4] = t;
            t[0]=bf2f(kb[0]); t[1]=bf2f(kb[1]); t[2]=bf2f(kb[2]); t[3]=bf2f(kb[3]);
            *(f32x4*)&kt[sj*64 + u1*4] = t;
            t[0]=bf2f(va[0]); t[1]=bf2f(va[1]); t[2]=bf2f(va[2]); t[3]=bf2f(va[3]);
            *(f32x4*)&vt[sj*64 + u0*4] = t;
            t[0]=bf2f(vb[0]); t[1]=bf2f(vb[1]); t[2]=bf2f(vb[2]); t[3]=bf2f(vb[3]);
            *(f32x4*)&vt[sj*64 + u1*4] = t;
        }
        __syncthreads();
        // scores: lane = j, wave handles agents g*8+wid
        float dots[7] = {0,0,0,0,0,0,0};
#pragma unroll 4
        for (int d4 = 0; d4 < 16; ++d4) {
            const f32x4 k4 = *(const f32x4*)&kt[lane*64 + ((d4 ^ (lane & 15)) * 4)];
#pragma unroll
            for (int g = 0; g < 7; ++g) {
                const f32x4 a4 = *(const f32x4*)&at_s[(g*8 + wid)*64 + d4*4];
                dots[g] = fmaf(a4[0], k4[0], dots[g]);
                dots[g] = fmaf(a4[1], k4[1], dots[g]);
                dots[g] = fmaf(a4[2], k4[2], dots[g]);
                dots[g] = fmaf(a4[3], k4[3], dots[g]);
            }
        }
#pragma unroll
        for (int g = 0; g < 7; ++g) {
            const int a = g*8 + wid;
            float e = 0.f;
            if (a < 49)
                e = __expf(fmaf(0.125f, dots[g], bias1[(h*49 + a)*1024 + jt*64 + lane]));
            e_s[a*64 + lane] = e;
        }
        // accumulate num/den: lane = d (reads own wave's e rows; no barrier needed)
#pragma unroll 4
        for (int j4 = 0; j4 < 16; ++j4) {
            f32x4 e4[7];
#pragma unroll
            for (int g = 0; g < 7; ++g) {
                e4[g] = *(const f32x4*)&e_s[(g*8 + wid)*64 + j4*4];
                den[g] += e4[g][0] + e4[g][1] + e4[g][2] + e4[g][3];
            }
#pragma unroll
            for (int i = 0; i < 4; ++i) {
                const int jj = j4*4 + i;
                const float vv = vt[jj*64 + ((((lane >> 2) ^ (jj & 15)) * 4) | (lane & 3))];
#pragma unroll
                for (int g = 0; g < 7; ++g) num[g] = fmaf(e4[g][i], vv, num[g]);
            }
        }
    }
#pragma unroll
    for (int g = 0; g < 7; ++g) {
        const int a = g*8 + wid;
        if (a < 49)
            agent_v[((size_t)(b*8 + h)*49 + a)*64 + lane] = num[g] / den[g];
    }
}

// ---------------------------------------------------------------------------
// Q attention + depthwise conv, fused. Block per (b,h), 512 thr.
// Phase 1: per token j: softmax_a(0.125*q.a_t + bias2) @ agent_v -> out_pre bf16
// Phase 2: coalesced RMW adding 3x3 depthwise conv of v.
// ---------------------------------------------------------------------------
__launch_bounds__(512)
__global__ void qattn_out_kernel(const unsigned short* __restrict__ qkv,
                                 const float* __restrict__ at_buf,
                                 const float* __restrict__ agent_v,
                                 const float* __restrict__ bias2,
                                 const float* __restrict__ dwc_w,
                                 const float* __restrict__ dwc_b,
                                 unsigned short* __restrict__ out_pre) {
    const int b = blockIdx.x >> 3, h = blockIdx.x & 7;
    __shared__ float at_s[49*64];
    __shared__ float av_s[49*64];
    for (int i = threadIdx.x; i < 49*64; i += 512) {
        const int a = i >> 6, d = i & 63;
        at_s[i] = at_buf[b*25088 + (a*8 + h)*64 + d];
        av_s[i] = agent_v[((size_t)(b*8 + h)*49 + a)*64 + d];
    }
    __syncthreads();

    for (int jj0 = 0; jj0 < 1024; jj0 += 512) {
        const int jj = jj0 + threadIdx.x;
        float qv[64];
        const unsigned short* qp = qkv + (size_t)(b*1024 + jj)*1536 + h*64;
#pragma unroll
        for (int i = 0; i < 16; ++i) {
            const u16x4 u = *(const u16x4*)(qp + i*4);
            qv[i*4+0]=bf2f(u[0]); qv[i*4+1]=bf2f(u[1]);
            qv[i*4+2]=bf2f(u[2]); qv[i*4+3]=bf2f(u[3]);
        }
        f32x4 acc[16];
#pragma unroll
        for (int i = 0; i < 16; ++i) acc[i] = (f32x4){0.f,0.f,0.f,0.f};
        float esum = 0.f;
        const float* b2 = bias2 + ((size_t)h*1024 + jj)*49;
        for (int a = 0; a < 49; ++a) {
            const float* ap = at_s + a*64;
            float dot = 0.f;
#pragma unroll
            for (int d4 = 0; d4 < 16; ++d4) {
                const f32x4 a4 = *(const f32x4*)(ap + d4*4);
                dot = fmaf(a4[0], qv[d4*4+0], dot);
                dot = fmaf(a4[1], qv[d4*4+1], dot);
                dot = fmaf(a4[2], qv[d4*4+2], dot);
                dot = fmaf(a4[3], qv[d4*4+3], dot);
            }
            const float e = __expf(fmaf(0.125f, dot, b2[a]));
            esum += e;
            const float* vp = av_s + a*64;
#pragma unroll
            for (int d4 = 0; d4 < 16; ++d4) {
                const f32x4 v4 = *(const f32x4*)(vp + d4*4);
                acc[d4][0] = fmaf(e, v4[0], acc[d4][0]);
                acc[d4][1] = fmaf(e, v4[1], acc[d4][1]);
                acc[d4][2] = fmaf(e, v4[2], acc[d4][2]);
                acc[d4][3] = fmaf(e, v4[3], acc[d4][3]);
            }
        }
        const float inv = 1.0f / esum;
        unsigned short* op = out_pre + (size_t)(b*1024 + jj)*512 + h*64;
#pragma unroll
        for (int d4 = 0; d4 < 16; ++d4) {
            u16x4 o;
            o[0]=f2bf(acc[d4][0]*inv); o[1]=f2bf(acc[d4][1]*inv);
            o[2]=f2bf(acc[d4][2]*inv); o[3]=f2bf(acc[d4][3]*inv);
            *(u16x4*)(op + d4*4) = o;
        }
    }
    __syncthreads();   // block-scope visibility of out_pre global writes

    // Phase 2: dwc RMW, lanes sweep channels (coalesced 8B)
    for (int it = 0; it < 32; ++it) {
        const int jj = it*32 + (threadIdx.x >> 4);
        const int c0 = (threadIdx.x & 15) * 4;
        const int y = jj >> 5, x = jj & 31;
        const int c = h*64 + c0;
        unsigned short* op = out_pre + (size_t)(b*1024 + jj)*512 + c;
        const u16x4 cur = *(const u16x4*)op;
        float o[4];
#pragma unroll
        for (int i = 0; i < 4; ++i) o[i] = bf2f(cur[i]) + dwc_b[c + i];
#pragma unroll
        for (int dy = 0; dy < 3; ++dy) {
            const int yy = y + dy - 1;
            if (yy < 0 || yy > 31) continue;
#pragma unroll
            for (int dx = 0; dx < 3; ++dx) {
                const int xx = x + dx - 1;
                if (xx < 0 || xx > 31) continue;
                const u16x4 v4 = *(const u16x4*)(qkv + (size_t)(b*1024 + yy*32 + xx)*1536 + 1024 + c);
#pragma unroll
                for (int i = 0; i < 4; ++i)
                    o[i] = fmaf(dwc_w[(c + i)*9 + dy*3 + dx], bf2f(v4[i]), o[i]);
            }
        }
        u16x4 nw;
#pragma unroll
        for (int i = 0; i < 4; ++i) nw[i] = f2bf(o[i]);
        *(u16x4*)op = nw;
    }
}

// ---------------------------------------------------------------------------
extern "C" void kernel_launch(void* const* d_in, const int* in_sizes, int n_in,
                              void* d_out, int out_size, void* d_ws, size_t ws_size,
                              hipStream_t stream) {
    (void)in_sizes; (void)n_in; (void)out_size; (void)ws_size;
    const float* x       = (const float*)d_in[0];
    const float* context = (const float*)d_in[1];
    const float* Wq      = (const float*)d_in[2];
    const float* Wkv     = (const float*)d_in[3];
    const float* conv_w  = (const float*)d_in[4];
    const float* conv_b  = (const float*)d_in[5];
    const float* dwc_w   = (const float*)d_in[6];
    const float* dwc_b   = (const float*)d_in[7];
    const float* proj_w  = (const float*)d_in[8];
    const float* proj_b  = (const float*)d_in[9];
    const float* an_bias = (const float*)d_in[10];
    const float* na_bias = (const float*)d_in[11];
    const float* ah_bias = (const float*)d_in[12];
    const float* aw_bias = (const float*)d_in[13];
    const float* ha_bias = (const float*)d_in[14];
    const float* wa_bias = (const float*)d_in[15];

    char* ws = (char*)d_ws;
    size_t off = 0;
    auto alloc = [&](size_t bytes) -> char* {
        char* p = ws + off; off += (bytes + 255) & ~(size_t)255; return p;
    };
    unsigned short* xb     = (unsigned short*)alloc((size_t)16777216 * 2);
    unsigned short* qkv    = (unsigned short*)alloc((size_t)50331648 * 2);
    unsigned short* wqkvt  = (unsigned short*)alloc((size_t)786432  * 2);
    unsigned short* projwt = (unsigned short*)alloc((size_t)262144  * 2);
    unsigned short* convwb = (unsigned short*)alloc((size_t)3538944 * 2);
    float*          pooled = (float*)alloc((size_t)1204224 * 4);
    unsigned short* i2c    = (unsigned short*)alloc((size_t)1664*6912*2); // padded to 13*128 rows
    float*          at_buf = (float*)alloc((size_t)802816 * 4);
    float*          bias1  = (float*)alloc((size_t)401408 * 4);
    float*          bias2  = (float*)alloc((size_t)401408 * 4);
    float*          agentv = (float*)alloc((size_t)802816 * 4);
    unsigned short* outpre = xb;   // alias: xb dead after qkv GEMM

    cvt_f32_bf16_kernel<<<16384, 256, 0, stream>>>(x, xb);
    cvt_f32_bf16_kernel<<<3456, 256, 0, stream>>>(conv_w, convwb);
    build_wqkvt_kernel<<<3072, 256, 0, stream>>>(Wq, Wkv, wqkvt);
    build_projwt_kernel<<<1024, 256, 0, stream>>>(proj_w, projwt);
    bias_prep_kernel<<<3136, 256, 0, stream>>>(an_bias, na_bias, ah_bias, aw_bias,
                                               ha_bias, wa_bias, bias1, bias2);
    // qkv = x @ [Wq|Wkv]  (M=32768, N=1536, K=512) -> bf16
    gemm_nt<1><<<dim3(12, 256), 256, 0, stream>>>(xb, wqkvt, qkv, nullptr, 512, 1536);
    pool_kernel<<<4704, 256, 0, stream>>>(qkv, context, pooled);
    im2col_kernel<<<42336, 256, 0, stream>>>(pooled, i2c);
    // conv as GEMM (M=1568 pad 1664, N=512, K=6912) -> a_t scatter + conv_b
    gemm_nt<2><<<dim3(4, 13), 256, 0, stream>>>(i2c, convwb, at_buf, conv_b, 6912, 0);
    agent_attn_kernel<<<256, 512, 0, stream>>>(qkv, at_buf, bias1, agentv);
    qattn_out_kernel<<<256, 512, 0, stream>>>(qkv, at_buf, agentv, bias2,
                                              dwc_w, dwc_b, outpre);
    // final: out_pre @ proj_w + proj_b  (M=32768, N=512, K=512) -> f32 d_out
    gemm_nt<0><<<dim3(4, 256), 256, 0, stream>>>(outpre, projwt, d_out, proj_b, 512, 512);
}

// Round 2
// 742.936 us; speedup vs baseline: 1.2202x; 1.2202x over previous
//
#include <hip/hip_runtime.h>
#include <stdint.h>

// ---------------------------------------------------------------------------
// Problem constants (fixed by setup_inputs)
// b=32, n=1024, dim=512, ic=512, cc=256, nh=8, ag=49, hd=64, H=W=c_H=c_W=32
// ---------------------------------------------------------------------------

typedef __attribute__((ext_vector_type(8)))  short          bf16x8;
typedef __attribute__((ext_vector_type(4)))  float          f32x4;
typedef __attribute__((ext_vector_type(4)))  unsigned short u16x4;

__device__ __forceinline__ float bf2f(unsigned short u) {
    union { unsigned int i; float f; } x; x.i = ((unsigned int)u) << 16; return x.f;
}
__device__ __forceinline__ unsigned short f2bf(float f) {
    union { float f; unsigned int i; } x; x.f = f;
    unsigned int i = x.i;
    i += 0x7FFFu + ((i >> 16) & 1u);   // RNE
    return (unsigned short)(i >> 16);
}

// ---------------------------------------------------------------------------
// Elementwise converters
// ---------------------------------------------------------------------------
__global__ void cvt_f32_bf16_kernel(const float* __restrict__ src,
                                    unsigned short* __restrict__ dst) {
    const int i = (blockIdx.x * 256 + threadIdx.x) * 4;
    const f32x4 v = *(const f32x4*)(src + i);
    u16x4 o; o[0]=f2bf(v[0]); o[1]=f2bf(v[1]); o[2]=f2bf(v[2]); o[3]=f2bf(v[3]);
    *(u16x4*)(dst + i) = o;
}

// Wqkv_t[nn][kk] (bf16, N=1536, K=512) from Wq (512,512) and Wkv (512,1024)
__global__ void build_wqkvt_kernel(const float* __restrict__ Wq,
                                   const float* __restrict__ Wkv,
                                   unsigned short* __restrict__ out) {
    const int idx = blockIdx.x * 256 + threadIdx.x;   // = nn*512 + kk
    if (idx >= 1536*512) return;
    const int nn = idx >> 9, kk = idx & 511;
    float v = (nn < 512) ? Wq[kk*512 + nn] : Wkv[kk*1024 + (nn - 512)];
    out[idx] = f2bf(v);
}

__global__ void build_projwt_kernel(const float* __restrict__ W,
                                    unsigned short* __restrict__ out) {
    const int idx = blockIdx.x * 256 + threadIdx.x;   // = nn*512 + kk
    if (idx >= 512*512) return;
    const int nn = idx >> 9, kk = idx & 511;
    out[idx] = f2bf(W[kk*512 + nn]);
}

// ---------------------------------------------------------------------------
// Bias precompute: bilinear 7->32 resize (jax.image.resize semantics:
// half-pixel centers, triangle kernel, edge weights renormalized == clamp)
// bias1[h][a][y*32+x] = resize(an_bias)[h,a,y,x] + ah[h,a,y] + aw[h,a,x]
// bias2[h][y*32+x][a] = resize(na_bias)[h,a,y,x] + ha[h,y,a] + wa[h,x,a]
// ---------------------------------------------------------------------------
__device__ __forceinline__ void bilin_coef(int i, int& i0, int& i1, float& f) {
    float pos = (i + 0.5f) * (7.0f / 32.0f) - 0.5f;
    float fl = floorf(pos);
    i0 = (int)fl; f = pos - fl;
    if (i0 < 0)       { i0 = 0; i1 = 0; f = 0.f; }
    else if (i0 >= 6) { i0 = 6; i1 = 6; f = 0.f; }
    else              { i1 = i0 + 1; }
}
__device__ __forceinline__ float bilin7(const float* __restrict__ s, int y, int x) {
    int y0,y1,x0,x1; float fy,fx;
    bilin_coef(y, y0, y1, fy); bilin_coef(x, x0, x1, fx);
    return (1.f-fy)*((1.f-fx)*s[y0*7+x0] + fx*s[y0*7+x1])
         +      fy *((1.f-fx)*s[y1*7+x0] + fx*s[y1*7+x1]);
}

__global__ void bias_prep_kernel(const float* __restrict__ an, const float* __restrict__ na,
                                 const float* __restrict__ ah, const float* __restrict__ aw,
                                 const float* __restrict__ ha, const float* __restrict__ wa,
                                 float* __restrict__ bias1, float* __restrict__ bias2) {
    int idx = blockIdx.x * 256 + threadIdx.x;
    if (idx < 8*49*1024) {
        const int nn = idx & 1023;
        const int a  = (idx >> 10) % 49;
        const int h  = idx / (49*1024);
        const int y = nn >> 5, x = nn & 31;
        float v = bilin7(an + (h*49 + a)*49, y, x)
                + ah[(h*49 + a)*32 + y] + aw[(h*49 + a)*32 + x];
        bias1[idx] = v;
    } else {
        idx -= 8*49*1024;
        if (idx >= 8*1024*49) return;
        const int a  = idx % 49;
        const int nn = (idx / 49) & 1023;
        const int h  = idx / (49*1024);
        const int y = nn >> 5, x = nn & 31;
        float v = bilin7(na + (h*49 + a)*49, y, x)
                + ha[h*1568 + y*49 + a] + wa[h*1568 + x*49 + a];
        bias2[idx] = v;
    }
}

// ---------------------------------------------------------------------------
// Adaptive avg-pool 32x32 -> 7x7 of q (from bf16 qkv cols 0..511) and context.
// pooled flat layout per batch: index a*768 + c
// ---------------------------------------------------------------------------
__global__ void pool_kernel(const unsigned short* __restrict__ qkv,
                            const float* __restrict__ context,
                            float* __restrict__ pooled) {
    const int idx = blockIdx.x * 256 + threadIdx.x;   // b*37632 + a*768 + c
    if (idx >= 32*49*768) return;
    const int c = idx % 768;
    const int a = (idx / 768) % 49;
    const int b = idx / (768*49);
    const int p = a / 7, q = a % 7;
    const int ys = p*32/7, ye = (p*32 + 38)/7;   // ceil((p+1)*32/7)
    const int xs = q*32/7, xe = (q*32 + 38)/7;
    float s = 0.f;
    if (c < 512) {
        for (int y = ys; y < ye; ++y)
            for (int x = xs; x < xe; ++x)
                s += bf2f(qkv[(size_t)(b*1024 + y*32 + x)*1536 + c]);
    } else {
        for (int y = ys; y < ye; ++y)
            for (int x = xs; x < xe; ++x)
                s += context[(size_t)(b*1024 + y*32 + x)*256 + (c - 512)];
    }
    pooled[idx] = s / (float)((ye - ys)*(xe - xs));
}

// im2col for the 3x3 pad-1 conv on the scrambled (768,7,7) view.
// out[(b*49 + p*7+q)*6912 + ci*9 + dy*3 + dx]
__global__ void im2col_kernel(const float* __restrict__ pooled,
                              unsigned short* __restrict__ i2c) {
    const int idx = blockIdx.x * 256 + threadIdx.x;
    if (idx >= 1568*6912) return;
    const int kk = idx % 6912;
    const int m  = idx / 6912;
    const int b = m / 49, spq = m % 49;
    const int p = spq / 7, q = spq % 7;
    const int ci = kk / 9, r = kk % 9;
    const int dy = r / 3, dx = r % 3;
    const int yy = p + dy - 1, xx = q + dx - 1;
    float v = 0.f;
    if (yy >= 0 && yy < 7 && xx >= 0 && xx < 7)
        v = pooled[b*37632 + ci*49 + yy*7 + xx];
    i2c[idx] = f2bf(v);
}

// ---------------------------------------------------------------------------
// NT bf16 MFMA GEMM (m97 structure), unchanged from round 1.
// ---------------------------------------------------------------------------
template <int MODE>
__launch_bounds__(256)
__global__ void gemm_nt(const unsigned short* __restrict__ A,
                        const unsigned short* __restrict__ Bt,
                        void* __restrict__ C,
                        const float* __restrict__ bias,
                        int K, int ldc) {
    __shared__ unsigned short As[128*64];
    __shared__ unsigned short Bs[128*64];
    const int tid  = threadIdx.x;
    const int wid  = tid >> 6;
    const int lane = tid & 63;
    const int m0 = blockIdx.y * 128;
    const int n0 = blockIdx.x * 128;
    const int wm = (wid >> 1) * 64;
    const int wn = (wid & 1) * 64;
    const int lrow = lane & 15;
    const int quad = lane >> 4;
    const int srow = lane >> 3;
    const int scol = ((lane & 7) ^ srow) * 8;

    f32x4 acc[4][4];
#pragma unroll
    for (int i = 0; i < 4; ++i)
#pragma unroll
        for (int j = 0; j < 4; ++j) acc[i][j] = (f32x4){0.f,0.f,0.f,0.f};

    for (int k0 = 0; k0 < K; k0 += 64) {
        __syncthreads();
#pragma unroll
        for (int i = 0; i < 4; ++i) {
            const int chunk = wid*4 + i;
            const int row = chunk*8 + srow;
            __builtin_amdgcn_global_load_lds(
                (const __attribute__((address_space(1))) void*)(A + (size_t)(m0 + row)*K + k0 + scol),
                (__attribute__((address_space(3))) void*)(As + chunk*512), 16, 0, 0);
            __builtin_amdgcn_global_load_lds(
                (const __attribute__((address_space(1))) void*)(Bt + (size_t)(n0 + row)*K + k0 + scol),
                (__attribute__((address_space(3))) void*)(Bs + chunk*512), 16, 0, 0);
        }
        __syncthreads();
#pragma unroll
        for (int kk = 0; kk < 2; ++kk) {
            bf16x8 af[4], bfr[4];
#pragma unroll
            for (int mt = 0; mt < 4; ++mt) {
                const int row = wm + mt*16 + lrow;
                const int u = (kk*4 + quad) ^ (row & 7);
                af[mt] = *(const bf16x8*)(As + row*64 + u*8);
            }
#pragma unroll
            for (int nt = 0; nt < 4; ++nt) {
                const int row = wn + nt*16 + lrow;
                const int u = (kk*4 + quad) ^ (row & 7);
                bfr[nt] = *(const bf16x8*)(Bs + row*64 + u*8);
            }
#pragma unroll
            for (int mt = 0; mt < 4; ++mt)
#pragma unroll
                for (int nt = 0; nt < 4; ++nt)
                    acc[mt][nt] = __builtin_amdgcn_mfma_f32_16x16x32_bf16(
                        af[mt], bfr[nt], acc[mt][nt], 0, 0, 0);
        }
    }
#pragma unroll
    for (int mt = 0; mt < 4; ++mt) {
#pragma unroll
        for (int nt = 0; nt < 4; ++nt) {
#pragma unroll
            for (int r = 0; r < 4; ++r) {
                const int m = m0 + wm + mt*16 + quad*4 + r;
                const int n = n0 + wn + nt*16 + lrow;
                const float v = acc[mt][nt][r];
                if (MODE == 0) {
                    ((float*)C)[(size_t)m*ldc + n] = v + bias[n];
                } else if (MODE == 1) {
                    ((unsigned short*)C)[(size_t)m*ldc + n] = f2bf(v);
                } else {
                    if (m < 1568) {
                        const int bb = m / 49, ss = m % 49;
                        ((float*)C)[bb*25088 + n*49 + ss] = v + bias[n];
                    }
                }
            }
        }
    }
}

// ---------------------------------------------------------------------------
// Agent attention: agent_v[b,h,a,:] = softmax_j(0.125*a_t.k_j + bias1) @ v
// Block per (b,h), 1024 thr (16 waves -> 50% occupancy). Each wave owns
// agents a = g*16 + wid (g<4, mask a<49). Same verified swizzles as round 1.
// ---------------------------------------------------------------------------
__launch_bounds__(1024)
__global__ void agent_attn_kernel(const unsigned short* __restrict__ qkv,
                                  const float* __restrict__ at_buf,
                                  const float* __restrict__ bias1,
                                  float* __restrict__ agent_v) {
    const int b = blockIdx.x >> 3, h = blockIdx.x & 7;
    __shared__ float at_s[64*64];
    __shared__ float e_s [64*64];
    __shared__ float kt  [64*64];
    __shared__ float vt  [64*64];
    const int tid = threadIdx.x;
    const int wid = tid >> 6, lane = tid & 63;

    for (int i = tid; i < 64*64; i += 1024) {
        const int a = i >> 6;
        at_s[i] = (a < 49) ? at_buf[b*25088 + (a*8 + h)*64 + (i & 63)] : 0.f;
    }
    float num[4] = {0,0,0,0};
    float den[4] = {0,0,0,0};
    const int sj = tid >> 4;          // staging row 0..63
    const int su = tid & 15;          // staging unit (4 floats)

    for (int jt = 0; jt < 16; ++jt) {
        __syncthreads();
        { // stage k & v tiles (bf16 -> f32, swizzled 16B units)
            const unsigned short* kp = qkv + (size_t)(b*1024 + jt*64 + sj)*1536 + 512 + h*64 + su*4;
            const unsigned short* vp = kp + 512;
            const u16x4 ka = *(const u16x4*)kp;
            const u16x4 va = *(const u16x4*)vp;
            const int u0 = su ^ (sj & 15);
            f32x4 t;
            t[0]=bf2f(ka[0]); t[1]=bf2f(ka[1]); t[2]=bf2f(ka[2]); t[3]=bf2f(ka[3]);
            *(f32x4*)&kt[sj*64 + u0*4] = t;
            t[0]=bf2f(va[0]); t[1]=bf2f(va[1]); t[2]=bf2f(va[2]); t[3]=bf2f(va[3]);
            *(f32x4*)&vt[sj*64 + u0*4] = t;
        }
        __syncthreads();
        // scores: lane = j, wave handles agents g*16+wid
        float dots[4] = {0,0,0,0};
#pragma unroll 4
        for (int d4 = 0; d4 < 16; ++d4) {
            const f32x4 k4 = *(const f32x4*)&kt[lane*64 + ((d4 ^ (lane & 15)) * 4)];
#pragma unroll
            for (int g = 0; g < 4; ++g) {
                const f32x4 a4 = *(const f32x4*)&at_s[(g*16 + wid)*64 + d4*4];
                dots[g] = fmaf(a4[0], k4[0], dots[g]);
                dots[g] = fmaf(a4[1], k4[1], dots[g]);
                dots[g] = fmaf(a4[2], k4[2], dots[g]);
                dots[g] = fmaf(a4[3], k4[3], dots[g]);
            }
        }
#pragma unroll
        for (int g = 0; g < 4; ++g) {
            const int a = g*16 + wid;
            float e = 0.f;
            if (a < 49)
                e = __expf(fmaf(0.125f, dots[g], bias1[(h*49 + a)*1024 + jt*64 + lane]));
            e_s[a*64 + lane] = e;
        }
        // accumulate num/den: lane = d (wave reads only its own agents' rows)
#pragma unroll 4
        for (int j4 = 0; j4 < 16; ++j4) {
            f32x4 e4[4];
#pragma unroll
            for (int g = 0; g < 4; ++g) {
                e4[g] = *(const f32x4*)&e_s[(g*16 + wid)*64 + j4*4];
                den[g] += e4[g][0] + e4[g][1] + e4[g][2] + e4[g][3];
            }
#pragma unroll
            for (int i = 0; i < 4; ++i) {
                const int jj = j4*4 + i;
                const float vv = vt[jj*64 + ((((lane >> 2) ^ (jj & 15)) * 4) | (lane & 3))];
#pragma unroll
                for (int g = 0; g < 4; ++g) num[g] = fmaf(e4[g][i], vv, num[g]);
            }
        }
    }
#pragma unroll
    for (int g = 0; g < 4; ++g) {
        const int a = g*16 + wid;
        if (a < 49)
            agent_v[((size_t)(b*8 + h)*49 + a)*64 + lane] = num[g] / den[g];
    }
}

// ---------------------------------------------------------------------------
// Q attention + depthwise conv, fused. Block per (b, h, 64-token tile):
// grid 4096, 256 thr. Thread = (token tt = tid>>2, quarter p = tid&3 of d).
// Partial dot over 16 dims, butterfly-summed across the 4-lane group; each
// lane accumulates its own 16-dim output slice. dwc added before the single
// bf16 store (no global RMW).
// ---------------------------------------------------------------------------
__launch_bounds__(256)
__global__ void qattn_fused_kernel(const unsigned short* __restrict__ qkv,
                                   const float* __restrict__ at_buf,
                                   const float* __restrict__ agent_v,
                                   const float* __restrict__ bias2,
                                   const float* __restrict__ dwc_w,
                                   const float* __restrict__ dwc_b,
                                   unsigned short* __restrict__ out_pre) {
    const int b = blockIdx.x >> 3, h = blockIdx.x & 7;
    const int tq = blockIdx.y;
    __shared__ float at_s[49*64];
    __shared__ float av_s[49*64];
    __shared__ float dwcw_s[64*9];
    __shared__ float dwcb_s[64];
    for (int i = threadIdx.x; i < 49*64; i += 256) {
        const int a = i >> 6, d = i & 63;
        at_s[i] = at_buf[b*25088 + (a*8 + h)*64 + d];
        av_s[i] = agent_v[((size_t)(b*8 + h)*49 + a)*64 + d];
    }
    for (int i = threadIdx.x; i < 64*9; i += 256) dwcw_s[i] = dwc_w[h*576 + i];
    if (threadIdx.x < 64) dwcb_s[threadIdx.x] = dwc_b[h*64 + threadIdx.x];
    __syncthreads();

    const int tt = threadIdx.x >> 2;        // token within tile (0..63)
    const int p  = threadIdx.x & 3;         // d-quarter (0..3)
    const int jj = tq*64 + tt;              // token within batch image
    const int d0 = p*16;

    // load this thread's q slice (16 dims)
    float qv[16];
    {
        const unsigned short* qp = qkv + (size_t)(b*1024 + jj)*1536 + h*64 + d0;
#pragma unroll
        for (int i = 0; i < 4; ++i) {
            const u16x4 u = *(const u16x4*)(qp + i*4);
            qv[i*4+0]=bf2f(u[0]); qv[i*4+1]=bf2f(u[1]);
            qv[i*4+2]=bf2f(u[2]); qv[i*4+3]=bf2f(u[3]);
        }
    }
    float acc[16];
#pragma unroll
    for (int i = 0; i < 16; ++i) acc[i] = 0.f;
    float den = 0.f;
    const float* b2 = bias2 + ((size_t)h*1024 + jj)*49;

    for (int a = 0; a < 49; ++a) {
        const float* ap = at_s + a*64 + d0;
        float dot = 0.f;
#pragma unroll
        for (int d4 = 0; d4 < 4; ++d4) {
            const f32x4 a4 = *(const f32x4*)(ap + d4*4);
            dot = fmaf(a4[0], qv[d4*4+0], dot);
            dot = fmaf(a4[1], qv[d4*4+1], dot);
            dot = fmaf(a4[2], qv[d4*4+2], dot);
            dot = fmaf(a4[3], qv[d4*4+3], dot);
        }
        dot += __shfl_xor(dot, 1);
        dot += __shfl_xor(dot, 2);
        const float e = __expf(fmaf(0.125f, dot, b2[a]));
        den += e;
        const float* vp = av_s + a*64 + d0;
#pragma unroll
        for (int d4 = 0; d4 < 4; ++d4) {
            const f32x4 v4 = *(const f32x4*)(vp + d4*4);
            acc[d4*4+0] = fmaf(e, v4[0], acc[d4*4+0]);
            acc[d4*4+1] = fmaf(e, v4[1], acc[d4*4+1]);
            acc[d4*4+2] = fmaf(e, v4[2], acc[d4*4+2]);
            acc[d4*4+3] = fmaf(e, v4[3], acc[d4*4+3]);
        }
    }
    const float inv = 1.0f / den;

    // depthwise conv on v for this thread's (token, 16 channels), fused
    float o[16];
#pragma unroll
    for (int i = 0; i < 16; ++i) o[i] = acc[i]*inv + dwcb_s[d0 + i];
    const int y = jj >> 5, x = jj & 31;
#pragma unroll
    for (int dy = 0; dy < 3; ++dy) {
        const int yy = y + dy - 1;
        if (yy < 0 || yy > 31) continue;
#pragma unroll
        for (int dx = 0; dx < 3; ++dx) {
            const int xx = x + dx - 1;
            if (xx < 0 || xx > 31) continue;
            const unsigned short* vp =
                qkv + (size_t)(b*1024 + yy*32 + xx)*1536 + 1024 + h*64 + d0;
#pragma unroll
            for (int i4 = 0; i4 < 4; ++i4) {
                const u16x4 v4 = *(const u16x4*)(vp + i4*4);
#pragma unroll
                for (int i = 0; i < 4; ++i)
                    o[i4*4+i] = fmaf(dwcw_s[(d0 + i4*4 + i)*9 + dy*3 + dx],
                                     bf2f(v4[i]), o[i4*4+i]);
            }
        }
    }
    unsigned short* op = out_pre + (size_t)(b*1024 + jj)*512 + h*64 + d0;
#pragma unroll
    for (int i4 = 0; i4 < 4; ++i4) {
        u16x4 w;
        w[0]=f2bf(o[i4*4+0]); w[1]=f2bf(o[i4*4+1]);
        w[2]=f2bf(o[i4*4+2]); w[3]=f2bf(o[i4*4+3]);
        *(u16x4*)(op + i4*4) = w;
    }
}

// ---------------------------------------------------------------------------
extern "C" void kernel_launch(void* const* d_in, const int* in_sizes, int n_in,
                              void* d_out, int out_size, void* d_ws, size_t ws_size,
                              hipStream_t stream) {
    (void)in_sizes; (void)n_in; (void)out_size; (void)ws_size;
    const float* x       = (const float*)d_in[0];
    const float* context = (const float*)d_in[1];
    const float* Wq      = (const float*)d_in[2];
    const float* Wkv     = (const float*)d_in[3];
    const float* conv_w  = (const float*)d_in[4];
    const float* conv_b  = (const float*)d_in[5];
    const float* dwc_w   = (const float*)d_in[6];
    const float* dwc_b   = (const float*)d_in[7];
    const float* proj_w  = (const float*)d_in[8];
    const float* proj_b  = (const float*)d_in[9];
    const float* an_bias = (const float*)d_in[10];
    const float* na_bias = (const float*)d_in[11];
    const float* ah_bias = (const float*)d_in[12];
    const float* aw_bias = (const float*)d_in[13];
    const float* ha_bias = (const float*)d_in[14];
    const float* wa_bias = (const float*)d_in[15];

    char* ws = (char*)d_ws;
    size_t off = 0;
    auto alloc = [&](size_t bytes) -> char* {
        char* p = ws + off; off += (bytes + 255) & ~(size_t)255; return p;
    };
    unsigned short* xb     = (unsigned short*)alloc((size_t)16777216 * 2);
    unsigned short* qkv    = (unsigned short*)alloc((size_t)50331648 * 2);
    unsigned short* wqkvt  = (unsigned short*)alloc((size_t)786432  * 2);
    unsigned short* projwt = (unsigned short*)alloc((size_t)262144  * 2);
    unsigned short* convwb = (unsigned short*)alloc((size_t)3538944 * 2);
    float*          pooled = (float*)alloc((size_t)1204224 * 4);
    unsigned short* i2c    = (unsigned short*)alloc((size_t)1664*6912*2);
    float*          at_buf = (float*)alloc((size_t)802816 * 4);
    float*          bias1  = (float*)alloc((size_t)401408 * 4);
    float*          bias2  = (float*)alloc((size_t)401408 * 4);
    float*          agentv = (float*)alloc((size_t)802816 * 4);
    unsigned short* outpre = xb;   // alias: xb dead after qkv GEMM

    cvt_f32_bf16_kernel<<<16384, 256, 0, stream>>>(x, xb);
    cvt_f32_bf16_kernel<<<3456, 256, 0, stream>>>(conv_w, convwb);
    build_wqkvt_kernel<<<3072, 256, 0, stream>>>(Wq, Wkv, wqkvt);
    build_projwt_kernel<<<1024, 256, 0, stream>>>(proj_w, projwt);
    bias_prep_kernel<<<3136, 256, 0, stream>>>(an_bias, na_bias, ah_bias, aw_bias,
                                               ha_bias, wa_bias, bias1, bias2);
    // qkv = x @ [Wq|Wkv]  (M=32768, N=1536, K=512) -> bf16
    gemm_nt<1><<<dim3(12, 256), 256, 0, stream>>>(xb, wqkvt, qkv, nullptr, 512, 1536);
    pool_kernel<<<4704, 256, 0, stream>>>(qkv, context, pooled);
    im2col_kernel<<<42336, 256, 0, stream>>>(pooled, i2c);
    // conv as GEMM (M=1568 pad 1664, N=512, K=6912) -> a_t scatter + conv_b
    gemm_nt<2><<<dim3(4, 13), 256, 0, stream>>>(i2c, convwb, at_buf, conv_b, 6912, 0);
    agent_attn_kernel<<<256, 1024, 0, stream>>>(qkv, at_buf, bias1, agentv);
    qattn_fused_kernel<<<dim3(256, 16), 256, 0, stream>>>(qkv, at_buf, agentv, bias2,
                                                          dwc_w, dwc_b, outpre);
    // final: out_pre @ proj_w + proj_b  (M=32768, N=512, K=512) -> f32 d_out
    gemm_nt<0><<<dim3(4, 256), 256, 0, stream>>>(outpre, projwt, d_out, proj_b, 512, 512);
}

// Round 3
// 656.263 us; speedup vs baseline: 1.3814x; 1.1321x over previous
//
#include <hip/hip_runtime.h>
#include <stdint.h>

// ---------------------------------------------------------------------------
// Problem constants (fixed by setup_inputs)
// b=32, n=1024, dim=512, ic=512, cc=256, nh=8, ag=49, hd=64, H=W=c_H=c_W=32
// ---------------------------------------------------------------------------

typedef __attribute__((ext_vector_type(8)))  short          bf16x8;
typedef __attribute__((ext_vector_type(4)))  float          f32x4;
typedef __attribute__((ext_vector_type(4)))  unsigned short u16x4;

__device__ __forceinline__ float bf2f(unsigned short u) {
    union { unsigned int i; float f; } x; x.i = ((unsigned int)u) << 16; return x.f;
}
__device__ __forceinline__ unsigned short f2bf(float f) {
    union { float f; unsigned int i; } x; x.f = f;
    unsigned int i = x.i;
    i += 0x7FFFu + ((i >> 16) & 1u);   // RNE
    return (unsigned short)(i >> 16);
}

// ---------------------------------------------------------------------------
// Elementwise converters
// ---------------------------------------------------------------------------
__global__ void cvt_f32_bf16_kernel(const float* __restrict__ src,
                                    unsigned short* __restrict__ dst) {
    const int i = (blockIdx.x * 256 + threadIdx.x) * 4;
    const f32x4 v = *(const f32x4*)(src + i);
    u16x4 o; o[0]=f2bf(v[0]); o[1]=f2bf(v[1]); o[2]=f2bf(v[2]); o[3]=f2bf(v[3]);
    *(u16x4*)(dst + i) = o;
}

// Wqkv_t[nn][kk] (bf16, N=1536, K=512) from Wq (512,512) and Wkv (512,1024)
__global__ void build_wqkvt_kernel(const float* __restrict__ Wq,
                                   const float* __restrict__ Wkv,
                                   unsigned short* __restrict__ out) {
    const int idx = blockIdx.x * 256 + threadIdx.x;   // = nn*512 + kk
    if (idx >= 1536*512) return;
    const int nn = idx >> 9, kk = idx & 511;
    float v = (nn < 512) ? Wq[kk*512 + nn] : Wkv[kk*1024 + (nn - 512)];
    out[idx] = f2bf(v);
}

__global__ void build_projwt_kernel(const float* __restrict__ W,
                                    unsigned short* __restrict__ out) {
    const int idx = blockIdx.x * 256 + threadIdx.x;   // = nn*512 + kk
    if (idx >= 512*512) return;
    const int nn = idx >> 9, kk = idx & 511;
    out[idx] = f2bf(W[kk*512 + nn]);
}

// ---------------------------------------------------------------------------
// Bias precompute (bilinear 7->32, clamp edges == jax renormalized triangle)
// ---------------------------------------------------------------------------
__device__ __forceinline__ void bilin_coef(int i, int& i0, int& i1, float& f) {
    float pos = (i + 0.5f) * (7.0f / 32.0f) - 0.5f;
    float fl = floorf(pos);
    i0 = (int)fl; f = pos - fl;
    if (i0 < 0)       { i0 = 0; i1 = 0; f = 0.f; }
    else if (i0 >= 6) { i0 = 6; i1 = 6; f = 0.f; }
    else              { i1 = i0 + 1; }
}
__device__ __forceinline__ float bilin7(const float* __restrict__ s, int y, int x) {
    int y0,y1,x0,x1; float fy,fx;
    bilin_coef(y, y0, y1, fy); bilin_coef(x, x0, x1, fx);
    return (1.f-fy)*((1.f-fx)*s[y0*7+x0] + fx*s[y0*7+x1])
         +      fy *((1.f-fx)*s[y1*7+x0] + fx*s[y1*7+x1]);
}

__global__ void bias_prep_kernel(const float* __restrict__ an, const float* __restrict__ na,
                                 const float* __restrict__ ah, const float* __restrict__ aw,
                                 const float* __restrict__ ha, const float* __restrict__ wa,
                                 float* __restrict__ bias1, float* __restrict__ bias2) {
    int idx = blockIdx.x * 256 + threadIdx.x;
    if (idx < 8*49*1024) {
        const int nn = idx & 1023;
        const int a  = (idx >> 10) % 49;
        const int h  = idx / (49*1024);
        const int y = nn >> 5, x = nn & 31;
        float v = bilin7(an + (h*49 + a)*49, y, x)
                + ah[(h*49 + a)*32 + y] + aw[(h*49 + a)*32 + x];
        bias1[idx] = v;
    } else {
        idx -= 8*49*1024;
        if (idx >= 8*1024*49) return;
        const int a  = idx % 49;
        const int nn = (idx / 49) & 1023;
        const int h  = idx / (49*1024);
        const int y = nn >> 5, x = nn & 31;
        float v = bilin7(na + (h*49 + a)*49, y, x)
                + ha[h*1568 + y*49 + a] + wa[h*1568 + x*49 + a];
        bias2[idx] = v;
    }
}

// ---------------------------------------------------------------------------
// Adaptive avg-pool 32x32 -> 7x7 ; pooled flat layout per batch: a*768 + c
// ---------------------------------------------------------------------------
__global__ void pool_kernel(const unsigned short* __restrict__ qkv,
                            const float* __restrict__ context,
                            float* __restrict__ pooled) {
    const int idx = blockIdx.x * 256 + threadIdx.x;   // b*37632 + a*768 + c
    if (idx >= 32*49*768) return;
    const int c = idx % 768;
    const int a = (idx / 768) % 49;
    const int b = idx / (768*49);
    const int p = a / 7, q = a % 7;
    const int ys = p*32/7, ye = (p*32 + 38)/7;
    const int xs = q*32/7, xe = (q*32 + 38)/7;
    float s = 0.f;
    if (c < 512) {
        for (int y = ys; y < ye; ++y)
            for (int x = xs; x < xe; ++x)
                s += bf2f(qkv[(size_t)(b*1024 + y*32 + x)*1536 + c]);
    } else {
        for (int y = ys; y < ye; ++y)
            for (int x = xs; x < xe; ++x)
                s += context[(size_t)(b*1024 + y*32 + x)*256 + (c - 512)];
    }
    pooled[idx] = s / (float)((ye - ys)*(xe - xs));
}

// im2col: out[(b*49 + p*7+q)*6912 + ci*9 + dy*3 + dx]
__global__ void im2col_kernel(const float* __restrict__ pooled,
                              unsigned short* __restrict__ i2c) {
    const int idx = blockIdx.x * 256 + threadIdx.x;
    if (idx >= 1568*6912) return;
    const int kk = idx % 6912;
    const int m  = idx / 6912;
    const int b = m / 49, spq = m % 49;
    const int p = spq / 7, q = spq % 7;
    const int ci = kk / 9, r = kk % 9;
    const int dy = r / 3, dx = r % 3;
    const int yy = p + dy - 1, xx = q + dx - 1;
    float v = 0.f;
    if (yy >= 0 && yy < 7 && xx >= 0 && xx < 7)
        v = pooled[b*37632 + ci*49 + yy*7 + xx];
    i2c[idx] = f2bf(v);
}

// ---------------------------------------------------------------------------
// NT bf16 MFMA GEMM (m97 structure) with split-K support.
// MODE 0: f32 C row-major + bias (proj)   MODE 1: bf16 C row-major (qkv)
// MODE 3: f32 partial tile to part[(z*1568 + m)*512 + n], mask m<1568 (conv)
// ---------------------------------------------------------------------------
template <int MODE>
__launch_bounds__(256)
__global__ void gemm_nt(const unsigned short* __restrict__ A,
                        const unsigned short* __restrict__ Bt,
                        void* __restrict__ C,
                        const float* __restrict__ bias,
                        int K, int ldc, int kspan) {
    __shared__ unsigned short As[128*64];
    __shared__ unsigned short Bs[128*64];
    const int tid  = threadIdx.x;
    const int wid  = tid >> 6;
    const int lane = tid & 63;
    const int m0 = blockIdx.y * 128;
    const int n0 = blockIdx.x * 128;
    const int wm = (wid >> 1) * 64;
    const int wn = (wid & 1) * 64;
    const int lrow = lane & 15;
    const int quad = lane >> 4;
    const int srow = lane >> 3;
    const int scol = ((lane & 7) ^ srow) * 8;

    f32x4 acc[4][4];
#pragma unroll
    for (int i = 0; i < 4; ++i)
#pragma unroll
        for (int j = 0; j < 4; ++j) acc[i][j] = (f32x4){0.f,0.f,0.f,0.f};

    const int kz0 = blockIdx.z * kspan;
    const int kz1 = min(K, kz0 + kspan);
    for (int k0 = kz0; k0 < kz1; k0 += 64) {
        __syncthreads();
#pragma unroll
        for (int i = 0; i < 4; ++i) {
            const int chunk = wid*4 + i;
            const int row = chunk*8 + srow;
            __builtin_amdgcn_global_load_lds(
                (const __attribute__((address_space(1))) void*)(A + (size_t)(m0 + row)*K + k0 + scol),
                (__attribute__((address_space(3))) void*)(As + chunk*512), 16, 0, 0);
            __builtin_amdgcn_global_load_lds(
                (const __attribute__((address_space(1))) void*)(Bt + (size_t)(n0 + row)*K + k0 + scol),
                (__attribute__((address_space(3))) void*)(Bs + chunk*512), 16, 0, 0);
        }
        __syncthreads();
#pragma unroll
        for (int kk = 0; kk < 2; ++kk) {
            bf16x8 af[4], bfr[4];
#pragma unroll
            for (int mt = 0; mt < 4; ++mt) {
                const int row = wm + mt*16 + lrow;
                const int u = (kk*4 + quad) ^ (row & 7);
                af[mt] = *(const bf16x8*)(As + row*64 + u*8);
            }
#pragma unroll
            for (int nt = 0; nt < 4; ++nt) {
                const int row = wn + nt*16 + lrow;
                const int u = (kk*4 + quad) ^ (row & 7);
                bfr[nt] = *(const bf16x8*)(Bs + row*64 + u*8);
            }
#pragma unroll
            for (int mt = 0; mt < 4; ++mt)
#pragma unroll
                for (int nt = 0; nt < 4; ++nt)
                    acc[mt][nt] = __builtin_amdgcn_mfma_f32_16x16x32_bf16(
                        af[mt], bfr[nt], acc[mt][nt], 0, 0, 0);
        }
    }
#pragma unroll
    for (int mt = 0; mt < 4; ++mt) {
#pragma unroll
        for (int nt = 0; nt < 4; ++nt) {
#pragma unroll
            for (int r = 0; r < 4; ++r) {
                const int m = m0 + wm + mt*16 + quad*4 + r;
                const int n = n0 + wn + nt*16 + lrow;
                const float v = acc[mt][nt][r];
                if (MODE == 0) {
                    ((float*)C)[(size_t)m*ldc + n] = v + bias[n];
                } else if (MODE == 1) {
                    ((unsigned short*)C)[(size_t)m*ldc + n] = f2bf(v);
                } else {
                    if (m < 1568)
                        ((float*)C)[((size_t)blockIdx.z*1568 + m)*512 + n] = v;
                }
            }
        }
    }
}

// Sum 9 split-K partials, add conv bias, scatter to a_t layout.
__global__ void convred_kernel(const float* __restrict__ part,
                               const float* __restrict__ bias,
                               float* __restrict__ at_buf) {
    const int idx = blockIdx.x * 256 + threadIdx.x;   // over 1568*128
    if (idx >= 1568*128) return;
    const int m  = idx >> 7;
    const int n4 = (idx & 127) * 4;
    f32x4 s = *(const f32x4*)&part[(size_t)m*512 + n4];
#pragma unroll
    for (int kz = 1; kz < 9; ++kz) {
        const f32x4 p = *(const f32x4*)&part[((size_t)kz*1568 + m)*512 + n4];
        s[0]+=p[0]; s[1]+=p[1]; s[2]+=p[2]; s[3]+=p[3];
    }
    const int bb = m / 49, ss = m % 49;
    float* o = at_buf + bb*25088 + ss;
    o[(n4+0)*49] = s[0] + bias[n4+0];
    o[(n4+1)*49] = s[1] + bias[n4+1];
    o[(n4+2)*49] = s[2] + bias[n4+2];
    o[(n4+3)*49] = s[3] + bias[n4+3];
}

// ---------------------------------------------------------------------------
// Agent attention, split over j: grid (256, 4), 1024 thr. Slice sl handles
// jt in [sl*4, sl*4+4). Softmax num/den are linear (no max-sub) -> partials.
// ---------------------------------------------------------------------------
__launch_bounds__(1024)
__global__ void agent_attn_kernel(const unsigned short* __restrict__ qkv,
                                  const float* __restrict__ at_buf,
                                  const float* __restrict__ bias1,
                                  float* __restrict__ pn,
                                  float* __restrict__ pd) {
    const int bh = blockIdx.x;
    const int b = bh >> 3, h = bh & 7;
    const int sl = blockIdx.y;
    __shared__ float at_s[64*64];
    __shared__ float e_s [64*64];
    __shared__ float kt  [64*64];
    __shared__ float vt  [64*64];
    const int tid = threadIdx.x;
    const int wid = tid >> 6, lane = tid & 63;

    for (int i = tid; i < 64*64; i += 1024) {
        const int a = i >> 6;
        at_s[i] = (a < 49) ? at_buf[b*25088 + (a*8 + h)*64 + (i & 63)] : 0.f;
    }
    float num[4] = {0,0,0,0};
    float den[4] = {0,0,0,0};
    const int sj = tid >> 4;
    const int su = tid & 15;

    for (int jt = sl*4; jt < sl*4 + 4; ++jt) {
        __syncthreads();
        {
            const unsigned short* kp = qkv + (size_t)(b*1024 + jt*64 + sj)*1536 + 512 + h*64 + su*4;
            const unsigned short* vp = kp + 512;
            const u16x4 ka = *(const u16x4*)kp;
            const u16x4 va = *(const u16x4*)vp;
            const int u0 = su ^ (sj & 15);
            f32x4 t;
            t[0]=bf2f(ka[0]); t[1]=bf2f(ka[1]); t[2]=bf2f(ka[2]); t[3]=bf2f(ka[3]);
            *(f32x4*)&kt[sj*64 + u0*4] = t;
            t[0]=bf2f(va[0]); t[1]=bf2f(va[1]); t[2]=bf2f(va[2]); t[3]=bf2f(va[3]);
            *(f32x4*)&vt[sj*64 + u0*4] = t;
        }
        __syncthreads();
        float dots[4] = {0,0,0,0};
#pragma unroll 4
        for (int d4 = 0; d4 < 16; ++d4) {
            const f32x4 k4 = *(const f32x4*)&kt[lane*64 + ((d4 ^ (lane & 15)) * 4)];
#pragma unroll
            for (int g = 0; g < 4; ++g) {
                const f32x4 a4 = *(const f32x4*)&at_s[(g*16 + wid)*64 + d4*4];
                dots[g] = fmaf(a4[0], k4[0], dots[g]);
                dots[g] = fmaf(a4[1], k4[1], dots[g]);
                dots[g] = fmaf(a4[2], k4[2], dots[g]);
                dots[g] = fmaf(a4[3], k4[3], dots[g]);
            }
        }
#pragma unroll
        for (int g = 0; g < 4; ++g) {
            const int a = g*16 + wid;
            float e = 0.f;
            if (a < 49)
                e = __expf(fmaf(0.125f, dots[g], bias1[(h*49 + a)*1024 + jt*64 + lane]));
            e_s[a*64 + lane] = e;
        }
#pragma unroll 4
        for (int j4 = 0; j4 < 16; ++j4) {
            f32x4 e4[4];
#pragma unroll
            for (int g = 0; g < 4; ++g) {
                e4[g] = *(const f32x4*)&e_s[(g*16 + wid)*64 + j4*4];
                den[g] += e4[g][0] + e4[g][1] + e4[g][2] + e4[g][3];
            }
#pragma unroll
            for (int i = 0; i < 4; ++i) {
                const int jj = j4*4 + i;
                const float vv = vt[jj*64 + ((((lane >> 2) ^ (jj & 15)) * 4) | (lane & 3))];
#pragma unroll
                for (int g = 0; g < 4; ++g) num[g] = fmaf(e4[g][i], vv, num[g]);
            }
        }
    }
#pragma unroll
    for (int g = 0; g < 4; ++g) {
        const int a = g*16 + wid;
        if (a < 49) {
            pn[(((size_t)bh*4 + sl)*49 + a)*64 + lane] = num[g];
            if (lane == 0) pd[((size_t)bh*4 + sl)*49 + a] = den[g];
        }
    }
}

__global__ void agent_combine_kernel(const float* __restrict__ pn,
                                     const float* __restrict__ pd,
                                     float* __restrict__ agent_v) {
    const int idx = blockIdx.x * 256 + threadIdx.x;   // < 256*49*64
    if (idx >= 256*49*64) return;
    const int d  = idx & 63;
    const int a  = (idx >> 6) % 49;
    const int bh = idx / (49*64);
    float num = 0.f, den = 0.f;
#pragma unroll
    for (int s = 0; s < 4; ++s) {
        num += pn[(((size_t)bh*4 + s)*49 + a)*64 + d];
        den += pd[((size_t)bh*4 + s)*49 + a];
    }
    agent_v[idx] = num / den;
}

// ---------------------------------------------------------------------------
// Q attention + depthwise conv, fused (unchanged from round 2).
// ---------------------------------------------------------------------------
__launch_bounds__(256)
__global__ void qattn_fused_kernel(const unsigned short* __restrict__ qkv,
                                   const float* __restrict__ at_buf,
                                   const float* __restrict__ agent_v,
                                   const float* __restrict__ bias2,
                                   const float* __restrict__ dwc_w,
                                   const float* __restrict__ dwc_b,
                                   unsigned short* __restrict__ out_pre) {
    const int b = blockIdx.x >> 3, h = blockIdx.x & 7;
    const int tq = blockIdx.y;
    __shared__ float at_s[49*64];
    __shared__ float av_s[49*64];
    __shared__ float dwcw_s[64*9];
    __shared__ float dwcb_s[64];
    for (int i = threadIdx.x; i < 49*64; i += 256) {
        const int a = i >> 6, d = i & 63;
        at_s[i] = at_buf[b*25088 + (a*8 + h)*64 + d];
        av_s[i] = agent_v[((size_t)(b*8 + h)*49 + a)*64 + d];
    }
    for (int i = threadIdx.x; i < 64*9; i += 256) dwcw_s[i] = dwc_w[h*576 + i];
    if (threadIdx.x < 64) dwcb_s[threadIdx.x] = dwc_b[h*64 + threadIdx.x];
    __syncthreads();

    const int tt = threadIdx.x >> 2;
    const int p  = threadIdx.x & 3;
    const int jj = tq*64 + tt;
    const int d0 = p*16;

    float qv[16];
    {
        const unsigned short* qp = qkv + (size_t)(b*1024 + jj)*1536 + h*64 + d0;
#pragma unroll
        for (int i = 0; i < 4; ++i) {
            const u16x4 u = *(const u16x4*)(qp + i*4);
            qv[i*4+0]=bf2f(u[0]); qv[i*4+1]=bf2f(u[1]);
            qv[i*4+2]=bf2f(u[2]); qv[i*4+3]=bf2f(u[3]);
        }
    }
    float acc[16];
#pragma unroll
    for (int i = 0; i < 16; ++i) acc[i] = 0.f;
    float den = 0.f;
    const float* b2 = bias2 + ((size_t)h*1024 + jj)*49;

    for (int a = 0; a < 49; ++a) {
        const float* ap = at_s + a*64 + d0;
        float dot = 0.f;
#pragma unroll
        for (int d4 = 0; d4 < 4; ++d4) {
            const f32x4 a4 = *(const f32x4*)(ap + d4*4);
            dot = fmaf(a4[0], qv[d4*4+0], dot);
            dot = fmaf(a4[1], qv[d4*4+1], dot);
            dot = fmaf(a4[2], qv[d4*4+2], dot);
            dot = fmaf(a4[3], qv[d4*4+3], dot);
        }
        dot += __shfl_xor(dot, 1);
        dot += __shfl_xor(dot, 2);
        const float e = __expf(fmaf(0.125f, dot, b2[a]));
        den += e;
        const float* vp = av_s + a*64 + d0;
#pragma unroll
        for (int d4 = 0; d4 < 4; ++d4) {
            const f32x4 v4 = *(const f32x4*)(vp + d4*4);
            acc[d4*4+0] = fmaf(e, v4[0], acc[d4*4+0]);
            acc[d4*4+1] = fmaf(e, v4[1], acc[d4*4+1]);
            acc[d4*4+2] = fmaf(e, v4[2], acc[d4*4+2]);
            acc[d4*4+3] = fmaf(e, v4[3], acc[d4*4+3]);
        }
    }
    const float inv = 1.0f / den;

    float o[16];
#pragma unroll
    for (int i = 0; i < 16; ++i) o[i] = acc[i]*inv + dwcb_s[d0 + i];
    const int y = jj >> 5, x = jj & 31;
#pragma unroll
    for (int dy = 0; dy < 3; ++dy) {
        const int yy = y + dy - 1;
        if (yy < 0 || yy > 31) continue;
#pragma unroll
        for (int dx = 0; dx < 3; ++dx) {
            const int xx = x + dx - 1;
            if (xx < 0 || xx > 31) continue;
            const unsigned short* vp =
                qkv + (size_t)(b*1024 + yy*32 + xx)*1536 + 1024 + h*64 + d0;
#pragma unroll
            for (int i4 = 0; i4 < 4; ++i4) {
                const u16x4 v4 = *(const u16x4*)(vp + i4*4);
#pragma unroll
                for (int i = 0; i < 4; ++i)
                    o[i4*4+i] = fmaf(dwcw_s[(d0 + i4*4 + i)*9 + dy*3 + dx],
                                     bf2f(v4[i]), o[i4*4+i]);
            }
        }
    }
    unsigned short* op = out_pre + (size_t)(b*1024 + jj)*512 + h*64 + d0;
#pragma unroll
    for (int i4 = 0; i4 < 4; ++i4) {
        u16x4 w;
        w[0]=f2bf(o[i4*4+0]); w[1]=f2bf(o[i4*4+1]);
        w[2]=f2bf(o[i4*4+2]); w[3]=f2bf(o[i4*4+3]);
        *(u16x4*)(op + i4*4) = w;
    }
}

// ---------------------------------------------------------------------------
extern "C" void kernel_launch(void* const* d_in, const int* in_sizes, int n_in,
                              void* d_out, int out_size, void* d_ws, size_t ws_size,
                              hipStream_t stream) {
    (void)in_sizes; (void)n_in; (void)out_size; (void)ws_size;
    const float* x       = (const float*)d_in[0];
    const float* context = (const float*)d_in[1];
    const float* Wq      = (const float*)d_in[2];
    const float* Wkv     = (const float*)d_in[3];
    const float* conv_w  = (const float*)d_in[4];
    const float* conv_b  = (const float*)d_in[5];
    const float* dwc_w   = (const float*)d_in[6];
    const float* dwc_b   = (const float*)d_in[7];
    const float* proj_w  = (const float*)d_in[8];
    const float* proj_b  = (const float*)d_in[9];
    const float* an_bias = (const float*)d_in[10];
    const float* na_bias = (const float*)d_in[11];
    const float* ah_bias = (const float*)d_in[12];
    const float* aw_bias = (const float*)d_in[13];
    const float* ha_bias = (const float*)d_in[14];
    const float* wa_bias = (const float*)d_in[15];

    char* ws = (char*)d_ws;
    size_t off = 0;
    auto alloc = [&](size_t bytes) -> char* {
        char* p = ws + off; off += (bytes + 255) & ~(size_t)255; return p;
    };
    unsigned short* xb     = (unsigned short*)alloc((size_t)16777216 * 2); // 33.5 MB
    unsigned short* qkv    = (unsigned short*)alloc((size_t)50331648 * 2);
    unsigned short* wqkvt  = (unsigned short*)alloc((size_t)786432  * 2);
    unsigned short* projwt = (unsigned short*)alloc((size_t)262144  * 2);
    unsigned short* convwb = (unsigned short*)alloc((size_t)3538944 * 2);
    float*          pooled = (float*)alloc((size_t)1204224 * 4);
    unsigned short* i2c    = (unsigned short*)alloc((size_t)1664*6912*2);  // 23 MB
    float*          at_buf = (float*)alloc((size_t)802816 * 4);
    float*          bias1  = (float*)alloc((size_t)401408 * 4);
    float*          bias2  = (float*)alloc((size_t)401408 * 4);
    float*          agentv = (float*)alloc((size_t)802816 * 4);
    // Aliases (stream-order safe):
    //  - conv split-K partials (9*1568*512*4 = 28.9 MB) live only between the
    //    conv GEMM and convred; xb (33.5 MB) is dead after the qkv GEMM and
    //    not rewritten (as outpre) until qattn_fused, which is later.
    //  - agent partials (12.8 MB + 0.2 MB) live only between agent_attn and
    //    agent_combine; i2c (23 MB) is dead after the conv GEMM.
    float*          part_conv = (float*)xb;
    float*          pn        = (float*)i2c;
    float*          pd        = pn + (size_t)4*256*49*64;
    unsigned short* outpre    = xb;   // written by qattn_fused (after convred)

    cvt_f32_bf16_kernel<<<16384, 256, 0, stream>>>(x, xb);
    cvt_f32_bf16_kernel<<<3456, 256, 0, stream>>>(conv_w, convwb);
    build_wqkvt_kernel<<<3072, 256, 0, stream>>>(Wq, Wkv, wqkvt);
    build_projwt_kernel<<<1024, 256, 0, stream>>>(proj_w, projwt);
    bias_prep_kernel<<<3136, 256, 0, stream>>>(an_bias, na_bias, ah_bias, aw_bias,
                                               ha_bias, wa_bias, bias1, bias2);
    // qkv = x @ [Wq|Wkv]  (M=32768, N=1536, K=512) -> bf16
    gemm_nt<1><<<dim3(12, 256), 256, 0, stream>>>(xb, wqkvt, qkv, nullptr, 512, 1536, 512);
    pool_kernel<<<4704, 256, 0, stream>>>(qkv, context, pooled);
    im2col_kernel<<<42336, 256, 0, stream>>>(pooled, i2c);
    // conv as split-K GEMM (M=1568 pad 1664, N=512, K=6912, 9 slices of 768)
    gemm_nt<3><<<dim3(4, 13, 9), 256, 0, stream>>>(i2c, convwb, part_conv, nullptr, 6912, 512, 768);
    convred_kernel<<<784, 256, 0, stream>>>(part_conv, conv_b, at_buf);
    // agent attention, 4 j-slices
    agent_attn_kernel<<<dim3(256, 4), 1024, 0, stream>>>(qkv, at_buf, bias1, pn, pd);
    agent_combine_kernel<<<3136, 256, 0, stream>>>(pn, pd, agentv);
    qattn_fused_kernel<<<dim3(256, 16), 256, 0, stream>>>(qkv, at_buf, agentv, bias2,
                                                          dwc_w, dwc_b, outpre);
    // final: out_pre @ proj_w + proj_b  (M=32768, N=512, K=512) -> f32 d_out
    gemm_nt<0><<<dim3(4, 256), 256, 0, stream>>>(outpre, projwt, d_out, proj_b, 512, 512, 512);
}

// Round 5
// 542.905 us; speedup vs baseline: 1.6698x; 1.2088x over previous
//
#include <hip/hip_runtime.h>
#include <stdint.h>

// ---------------------------------------------------------------------------
// Problem constants (fixed by setup_inputs)
// b=32, n=1024, dim=512, ic=512, cc=256, nh=8, ag=49, hd=64, H=W=c_H=c_W=32
// ---------------------------------------------------------------------------

typedef __attribute__((ext_vector_type(8)))  short          bf16x8;
typedef __attribute__((ext_vector_type(4)))  float          f32x4;
typedef __attribute__((ext_vector_type(4)))  unsigned short u16x4;

__device__ __forceinline__ float bf2f(unsigned short u) {
    union { unsigned int i; float f; } x; x.i = ((unsigned int)u) << 16; return x.f;
}
__device__ __forceinline__ unsigned short f2bf(float f) {
    union { float f; unsigned int i; } x; x.f = f;
    unsigned int i = x.i;
    i += 0x7FFFu + ((i >> 16) & 1u);   // RNE
    return (unsigned short)(i >> 16);
}

// ---------------------------------------------------------------------------
// Elementwise converters
// ---------------------------------------------------------------------------
__global__ void cvt_f32_bf16_kernel(const float* __restrict__ src,
                                    unsigned short* __restrict__ dst) {
    const int i = (blockIdx.x * 256 + threadIdx.x) * 4;
    const f32x4 v = *(const f32x4*)(src + i);
    u16x4 o; o[0]=f2bf(v[0]); o[1]=f2bf(v[1]); o[2]=f2bf(v[2]); o[3]=f2bf(v[3]);
    *(u16x4*)(dst + i) = o;
}

// Wqkv_t[nn][kk] (bf16, N=1536, K=512) from Wq (512,512) and Wkv (512,1024)
__global__ void build_wqkvt_kernel(const float* __restrict__ Wq,
                                   const float* __restrict__ Wkv,
                                   unsigned short* __restrict__ out) {
    const int idx = blockIdx.x * 256 + threadIdx.x;   // = nn*512 + kk
    if (idx >= 1536*512) return;
    const int nn = idx >> 9, kk = idx & 511;
    float v = (nn < 512) ? Wq[kk*512 + nn] : Wkv[kk*1024 + (nn - 512)];
    out[idx] = f2bf(v);
}

__global__ void build_projwt_kernel(const float* __restrict__ W,
                                    unsigned short* __restrict__ out) {
    const int idx = blockIdx.x * 256 + threadIdx.x;   // = nn*512 + kk
    if (idx >= 512*512) return;
    const int nn = idx >> 9, kk = idx & 511;
    out[idx] = f2bf(W[kk*512 + nn]);
}

// ---------------------------------------------------------------------------
// Bias precompute (bilinear 7->32, clamp edges == jax renormalized triangle)
// ---------------------------------------------------------------------------
__device__ __forceinline__ void bilin_coef(int i, int& i0, int& i1, float& f) {
    float pos = (i + 0.5f) * (7.0f / 32.0f) - 0.5f;
    float fl = floorf(pos);
    i0 = (int)fl; f = pos - fl;
    if (i0 < 0)       { i0 = 0; i1 = 0; f = 0.f; }
    else if (i0 >= 6) { i0 = 6; i1 = 6; f = 0.f; }
    else              { i1 = i0 + 1; }
}
__device__ __forceinline__ float bilin7(const float* __restrict__ s, int y, int x) {
    int y0,y1,x0,x1; float fy,fx;
    bilin_coef(y, y0, y1, fy); bilin_coef(x, x0, x1, fx);
    return (1.f-fy)*((1.f-fx)*s[y0*7+x0] + fx*s[y0*7+x1])
         +      fy *((1.f-fx)*s[y1*7+x0] + fx*s[y1*7+x1]);
}

__global__ void bias_prep_kernel(const float* __restrict__ an, const float* __restrict__ na,
                                 const float* __restrict__ ah, const float* __restrict__ aw,
                                 const float* __restrict__ ha, const float* __restrict__ wa,
                                 float* __restrict__ bias1, float* __restrict__ bias2) {
    int idx = blockIdx.x * 256 + threadIdx.x;
    if (idx < 8*49*1024) {
        const int nn = idx & 1023;
        const int a  = (idx >> 10) % 49;
        const int h  = idx / (49*1024);
        const int y = nn >> 5, x = nn & 31;
        float v = bilin7(an + (h*49 + a)*49, y, x)
                + ah[(h*49 + a)*32 + y] + aw[(h*49 + a)*32 + x];
        bias1[idx] = v;
    } else {
        idx -= 8*49*1024;
        if (idx >= 8*1024*49) return;
        const int a  = idx % 49;
        const int nn = (idx / 49) & 1023;
        const int h  = idx / (49*1024);
        const int y = nn >> 5, x = nn & 31;
        float v = bilin7(na + (h*49 + a)*49, y, x)
                + ha[h*1568 + y*49 + a] + wa[h*1568 + x*49 + a];
        bias2[idx] = v;
    }
}

// ---------------------------------------------------------------------------
// Adaptive avg-pool 32x32 -> 7x7 ; pooled flat layout per batch: a*768 + c
// ---------------------------------------------------------------------------
__global__ void pool_kernel(const unsigned short* __restrict__ qkv,
                            const float* __restrict__ context,
                            float* __restrict__ pooled) {
    const int idx = blockIdx.x * 256 + threadIdx.x;   // b*37632 + a*768 + c
    if (idx >= 32*49*768) return;
    const int c = idx % 768;
    const int a = (idx / 768) % 49;
    const int b = idx / (768*49);
    const int p = a / 7, q = a % 7;
    const int ys = p*32/7, ye = (p*32 + 38)/7;
    const int xs = q*32/7, xe = (q*32 + 38)/7;
    float s = 0.f;
    if (c < 512) {
        for (int y = ys; y < ye; ++y)
            for (int x = xs; x < xe; ++x)
                s += bf2f(qkv[(size_t)(b*1024 + y*32 + x)*1536 + c]);
    } else {
        for (int y = ys; y < ye; ++y)
            for (int x = xs; x < xe; ++x)
                s += context[(size_t)(b*1024 + y*32 + x)*256 + (c - 512)];
    }
    pooled[idx] = s / (float)((ye - ys)*(xe - xs));
}

// im2col: out[(b*49 + p*7+q)*6912 + ci*9 + dy*3 + dx]
__global__ void im2col_kernel(const float* __restrict__ pooled,
                              unsigned short* __restrict__ i2c) {
    const int idx = blockIdx.x * 256 + threadIdx.x;
    if (idx >= 1568*6912) return;
    const int kk = idx % 6912;
    const int m  = idx / 6912;
    const int b = m / 49, spq = m % 49;
    const int p = spq / 7, q = spq % 7;
    const int ci = kk / 9, r = kk % 9;
    const int dy = r / 3, dx = r % 3;
    const int yy = p + dy - 1, xx = q + dx - 1;
    float v = 0.f;
    if (yy >= 0 && yy < 7 && xx >= 0 && xx < 7)
        v = pooled[b*37632 + ci*49 + yy*7 + xx];
    i2c[idx] = f2bf(v);
}

// ---------------------------------------------------------------------------
// NT bf16 MFMA GEMM (m97 structure) with split-K support.
// MODE 0: f32 C row-major + bias (proj)   MODE 1: bf16 C row-major (qkv)
// MODE 3: f32 partial tile to part[(z*1568 + m)*512 + n], mask m<1568 (conv)
// ---------------------------------------------------------------------------
template <int MODE>
__launch_bounds__(256)
__global__ void gemm_nt(const unsigned short* __restrict__ A,
                        const unsigned short* __restrict__ Bt,
                        void* __restrict__ C,
                        const float* __restrict__ bias,
                        int K, int ldc, int kspan) {
    __shared__ unsigned short As[128*64];
    __shared__ unsigned short Bs[128*64];
    const int tid  = threadIdx.x;
    const int wid  = tid >> 6;
    const int lane = tid & 63;
    const int m0 = blockIdx.y * 128;
    const int n0 = blockIdx.x * 128;
    const int wm = (wid >> 1) * 64;
    const int wn = (wid & 1) * 64;
    const int lrow = lane & 15;
    const int quad = lane >> 4;
    const int srow = lane >> 3;
    const int scol = ((lane & 7) ^ srow) * 8;

    f32x4 acc[4][4];
#pragma unroll
    for (int i = 0; i < 4; ++i)
#pragma unroll
        for (int j = 0; j < 4; ++j) acc[i][j] = (f32x4){0.f,0.f,0.f,0.f};

    const int kz0 = blockIdx.z * kspan;
    const int kz1 = min(K, kz0 + kspan);
    for (int k0 = kz0; k0 < kz1; k0 += 64) {
        __syncthreads();
#pragma unroll
        for (int i = 0; i < 4; ++i) {
            const int chunk = wid*4 + i;
            const int row = chunk*8 + srow;
            __builtin_amdgcn_global_load_lds(
                (const __attribute__((address_space(1))) void*)(A + (size_t)(m0 + row)*K + k0 + scol),
                (__attribute__((address_space(3))) void*)(As + chunk*512), 16, 0, 0);
            __builtin_amdgcn_global_load_lds(
                (const __attribute__((address_space(1))) void*)(Bt + (size_t)(n0 + row)*K + k0 + scol),
                (__attribute__((address_space(3))) void*)(Bs + chunk*512), 16, 0, 0);
        }
        __syncthreads();
#pragma unroll
        for (int kk = 0; kk < 2; ++kk) {
            bf16x8 af[4], bfr[4];
#pragma unroll
            for (int mt = 0; mt < 4; ++mt) {
                const int row = wm + mt*16 + lrow;
                const int u = (kk*4 + quad) ^ (row & 7);
                af[mt] = *(const bf16x8*)(As + row*64 + u*8);
            }
#pragma unroll
            for (int nt = 0; nt < 4; ++nt) {
                const int row = wn + nt*16 + lrow;
                const int u = (kk*4 + quad) ^ (row & 7);
                bfr[nt] = *(const bf16x8*)(Bs + row*64 + u*8);
            }
#pragma unroll
            for (int mt = 0; mt < 4; ++mt)
#pragma unroll
                for (int nt = 0; nt < 4; ++nt)
                    acc[mt][nt] = __builtin_amdgcn_mfma_f32_16x16x32_bf16(
                        af[mt], bfr[nt], acc[mt][nt], 0, 0, 0);
        }
    }
#pragma unroll
    for (int mt = 0; mt < 4; ++mt) {
#pragma unroll
        for (int nt = 0; nt < 4; ++nt) {
#pragma unroll
            for (int r = 0; r < 4; ++r) {
                const int m = m0 + wm + mt*16 + quad*4 + r;
                const int n = n0 + wn + nt*16 + lrow;
                const float v = acc[mt][nt][r];
                if (MODE == 0) {
                    ((float*)C)[(size_t)m*ldc + n] = v + bias[n];
                } else if (MODE == 1) {
                    ((unsigned short*)C)[(size_t)m*ldc + n] = f2bf(v);
                } else {
                    if (m < 1568)
                        ((float*)C)[((size_t)blockIdx.z*1568 + m)*512 + n] = v;
                }
            }
        }
    }
}

// Sum 9 split-K partials, add conv bias, scatter to a_t layout.
__global__ void convred_kernel(const float* __restrict__ part,
                               const float* __restrict__ bias,
                               float* __restrict__ at_buf) {
    const int idx = blockIdx.x * 256 + threadIdx.x;   // over 1568*128
    if (idx >= 1568*128) return;
    const int m  = idx >> 7;
    const int n4 = (idx & 127) * 4;
    f32x4 s = *(const f32x4*)&part[(size_t)m*512 + n4];
#pragma unroll
    for (int kz = 1; kz < 9; ++kz) {
        const f32x4 p = *(const f32x4*)&part[((size_t)kz*1568 + m)*512 + n4];
        s[0]+=p[0]; s[1]+=p[1]; s[2]+=p[2]; s[3]+=p[3];
    }
    const int bb = m / 49, ss = m % 49;
    float* o = at_buf + bb*25088 + ss;
    o[(n4+0)*49] = s[0] + bias[n4+0];
    o[(n4+1)*49] = s[1] + bias[n4+1];
    o[(n4+2)*49] = s[2] + bias[n4+2];
    o[(n4+3)*49] = s[3] + bias[n4+3];
}

// ---------------------------------------------------------------------------
// MFMA agent attention. Grid (256 bh, 4 slices), 256 thr (4 waves).
// Wave w handles j in [sl*256 + w*64, +64).
// Scores: S[a(64 pad)][64 j] = a_t @ K^T. exp fp32 -> P bf16 LDS [a][j].
// PV as out^T = V^T @ P^T. Then IN-BLOCK cross-wave reduction (the round-4
// bug was 4 waves racing on pn[bh,sl]): P_s/V_s smem is re-carved as fp32
// red[4][64*64] + dred[4][64]; waves deposit partials, block sums, ONE
// pn/pd write per (bh,sl). Combine kernel divides.
// a_t flat layout within batch is the raw-reshape scramble: a*512 + h*64 + d.
// ---------------------------------------------------------------------------
__launch_bounds__(256)
__global__ void agent_attn_mfma_kernel(const unsigned short* __restrict__ qkv,
                                       const float* __restrict__ at_buf,
                                       const float* __restrict__ bias1,
                                       float* __restrict__ pn,
                                       float* __restrict__ pd) {
    const int bh = blockIdx.x;
    const int b = bh >> 3, h = bh & 7;
    const int sl = blockIdx.y;
    __shared__ unsigned short at_s[64*72];              // [a][d] pad 72
    __shared__ __align__(16) unsigned char smem[4*64*72*2 + 4*64*64*2]; // 69632 B
    unsigned short* P_s = (unsigned short*)smem;        // [4][64*72] bf16
    unsigned short* V_s = (unsigned short*)(smem + 36864); // [4][64*64] bf16
    float* red  = (float*)smem;                         // [4][64*64] f32 (65536 B)
    float* dred = (float*)(smem + 65536);               // [4][64] f32
    const int tid  = threadIdx.x;
    const int wid  = tid >> 6, lane = tid & 63;
    const int l15  = lane & 15, quad = lane >> 4;
    const int j0   = sl*256 + wid*64;

    for (int i = tid; i < 64*72; i += 256) at_s[i] = 0;
    __syncthreads();
    // stage a_t -> bf16 [a][d]; source flat index a*512 + h*64 + d (coalesced)
    for (int i = tid; i < 49*64; i += 256) {
        const int a = i >> 6, d = i & 63;
        at_s[a*72 + d] = f2bf(at_buf[b*25088 + a*512 + h*64 + d]);
    }
    // stage V rows j0..j0+63 -> V_s[wid] via global_load_lds (16B/lane)
#pragma unroll
    for (int i = 0; i < 8; ++i) {
        __builtin_amdgcn_global_load_lds(
            (const __attribute__((address_space(1))) void*)
                (qkv + (size_t)(b*1024 + j0 + i*8 + (lane>>3))*1536 + 1024 + h*64 + (lane&7)*8),
            (__attribute__((address_space(3))) void*)(V_s + wid*4096 + i*512), 16, 0, 0);
    }
    // K B-frags straight from global: n=j (lane&15), k=d contiguous
    bf16x8 kfr[4][2];
#pragma unroll
    for (int nt = 0; nt < 4; ++nt)
#pragma unroll
        for (int kf = 0; kf < 2; ++kf)
            kfr[nt][kf] = *(const bf16x8*)
                (qkv + (size_t)(b*1024 + j0 + nt*16 + l15)*1536 + 512 + h*64 + kf*32 + quad*8);
    __syncthreads();   // at_s ready; vmcnt drained -> V_s complete

    bf16x8 af[4][2];
#pragma unroll
    for (int mt = 0; mt < 4; ++mt)
#pragma unroll
        for (int kf = 0; kf < 2; ++kf)
            af[mt][kf] = *(const bf16x8*)(at_s + (mt*16 + l15)*72 + kf*32 + quad*8);

    f32x4 acc[4][4];
#pragma unroll
    for (int i = 0; i < 4; ++i)
#pragma unroll
        for (int j = 0; j < 4; ++j) acc[i][j] = (f32x4){0.f,0.f,0.f,0.f};
#pragma unroll
    for (int kf = 0; kf < 2; ++kf)
#pragma unroll
        for (int mt = 0; mt < 4; ++mt)
#pragma unroll
            for (int nt = 0; nt < 4; ++nt)
                acc[mt][nt] = __builtin_amdgcn_mfma_f32_16x16x32_bf16(
                    af[mt][kf], kfr[nt][kf], acc[mt][nt], 0, 0, 0);

    // bias + exp (fp32), P -> LDS, den partials
    float denp[4][4];
#pragma unroll
    for (int mt = 0; mt < 4; ++mt)
#pragma unroll
        for (int r = 0; r < 4; ++r) denp[mt][r] = 0.f;
#pragma unroll
    for (int mt = 0; mt < 4; ++mt) {
#pragma unroll
        for (int nt = 0; nt < 4; ++nt) {
#pragma unroll
            for (int r = 0; r < 4; ++r) {
                const int a  = mt*16 + quad*4 + r;
                const int ab = (a < 49) ? a : 48;
                const int jj = j0 + nt*16 + l15;
                const float e = __expf(fmaf(0.125f, acc[mt][nt][r],
                                            bias1[(h*49 + ab)*1024 + jj]));
                denp[mt][r] += e;
                P_s[wid*4608 + a*72 + nt*16 + l15] = f2bf(e);
            }
        }
    }
    __syncthreads();   // P_s visible

    // PV: out^T[d][a] = V^T @ P^T  (each wave: its own 64-j chunk)
    f32x4 out[4][4];
#pragma unroll
    for (int i = 0; i < 4; ++i)
#pragma unroll
        for (int j = 0; j < 4; ++j) out[i][j] = (f32x4){0.f,0.f,0.f,0.f};
#pragma unroll
    for (int kf = 0; kf < 2; ++kf) {
        bf16x8 va[4];
#pragma unroll
        for (int mt = 0; mt < 4; ++mt) {
            union { bf16x8 v; unsigned short s[8]; } u;
#pragma unroll
            for (int t = 0; t < 8; ++t)
                u.s[t] = V_s[wid*4096 + (kf*32 + quad*8 + t)*64 + mt*16 + l15];
            va[mt] = u.v;
        }
#pragma unroll
        for (int nt = 0; nt < 4; ++nt) {
            const bf16x8 pb = *(const bf16x8*)(P_s + wid*4608 + (nt*16 + l15)*72 + kf*32 + quad*8);
#pragma unroll
            for (int mt = 0; mt < 4; ++mt)
                out[mt][nt] = __builtin_amdgcn_mfma_f32_16x16x32_bf16(
                    va[mt], pb, out[mt][nt], 0, 0, 0);
        }
    }

    // den: reduce over the 16 j-column lanes (within quad group)
#pragma unroll
    for (int mt = 0; mt < 4; ++mt) {
#pragma unroll
        for (int r = 0; r < 4; ++r) {
            float v = denp[mt][r];
            v += __shfl_xor(v, 1);
            v += __shfl_xor(v, 2);
            v += __shfl_xor(v, 4);
            v += __shfl_xor(v, 8);
            denp[mt][r] = v;
        }
    }

    // ---- in-block cross-wave reduction (fixes the round-4 race) ----
    __syncthreads();   // all waves done reading P_s/V_s; safe to re-carve
#pragma unroll
    for (int nt = 0; nt < 4; ++nt) {
        const int a = nt*16 + l15;
#pragma unroll
        for (int mt = 0; mt < 4; ++mt)
            *(f32x4*)&red[wid*4096 + a*64 + mt*16 + quad*4] = out[mt][nt];
    }
    if (l15 == 0) {
#pragma unroll
        for (int mt = 0; mt < 4; ++mt)
#pragma unroll
            for (int r = 0; r < 4; ++r)
                dred[wid*64 + mt*16 + quad*4 + r] = denp[mt][r];
    }
    __syncthreads();
    for (int i = tid; i < 4096; i += 256) {
        const float s = red[i] + red[4096 + i] + red[8192 + i] + red[12288 + i];
        pn[((size_t)bh*4 + sl)*4096 + i] = s;   // i = a*64 + d
    }
    if (tid < 64) {
        const float s = dred[tid] + dred[64 + tid] + dred[128 + tid] + dred[192 + tid];
        pd[((size_t)bh*4 + sl)*64 + tid] = s;
    }
}

__global__ void agent_combine_kernel(const float* __restrict__ pn,
                                     const float* __restrict__ pd,
                                     float* __restrict__ agent_v) {
    const int idx = blockIdx.x * 256 + threadIdx.x;   // < 256*49*64
    if (idx >= 256*49*64) return;
    const int d  = idx & 63;
    const int a  = (idx >> 6) % 49;
    const int bh = idx / (49*64);
    float num = 0.f, den = 0.f;
#pragma unroll
    for (int s = 0; s < 4; ++s) {
        num += pn[(((size_t)bh*4 + s)*64 + a)*64 + d];
        den += pd[((size_t)bh*4 + s)*64 + a];
    }
    agent_v[idx] = num / den;
}

// ---------------------------------------------------------------------------
// Q attention + depthwise conv, fused (unchanged).
// ---------------------------------------------------------------------------
__launch_bounds__(256)
__global__ void qattn_fused_kernel(const unsigned short* __restrict__ qkv,
                                   const float* __restrict__ at_buf,
                                   const float* __restrict__ agent_v,
                                   const float* __restrict__ bias2,
                                   const float* __restrict__ dwc_w,
                                   const float* __restrict__ dwc_b,
                                   unsigned short* __restrict__ out_pre) {
    const int b = blockIdx.x >> 3, h = blockIdx.x & 7;
    const int tq = blockIdx.y;
    __shared__ float at_s[49*64];
    __shared__ float av_s[49*64];
    __shared__ float dwcw_s[64*9];
    __shared__ float dwcb_s[64];
    for (int i = threadIdx.x; i < 49*64; i += 256) {
        const int a = i >> 6, d = i & 63;
        at_s[i] = at_buf[b*25088 + (a*8 + h)*64 + d];
        av_s[i] = agent_v[((size_t)(b*8 + h)*49 + a)*64 + d];
    }
    for (int i = threadIdx.x; i < 64*9; i += 256) dwcw_s[i] = dwc_w[h*576 + i];
    if (threadIdx.x < 64) dwcb_s[threadIdx.x] = dwc_b[h*64 + threadIdx.x];
    __syncthreads();

    const int tt = threadIdx.x >> 2;
    const int p  = threadIdx.x & 3;
    const int jj = tq*64 + tt;
    const int d0 = p*16;

    float qv[16];
    {
        const unsigned short* qp = qkv + (size_t)(b*1024 + jj)*1536 + h*64 + d0;
#pragma unroll
        for (int i = 0; i < 4; ++i) {
            const u16x4 u = *(const u16x4*)(qp + i*4);
            qv[i*4+0]=bf2f(u[0]); qv[i*4+1]=bf2f(u[1]);
            qv[i*4+2]=bf2f(u[2]); qv[i*4+3]=bf2f(u[3]);
        }
    }
    float acc[16];
#pragma unroll
    for (int i = 0; i < 16; ++i) acc[i] = 0.f;
    float den = 0.f;
    const float* b2 = bias2 + ((size_t)h*1024 + jj)*49;

    for (int a = 0; a < 49; ++a) {
        const float* ap = at_s + a*64 + d0;
        float dot = 0.f;
#pragma unroll
        for (int d4 = 0; d4 < 4; ++d4) {
            const f32x4 a4 = *(const f32x4*)(ap + d4*4);
            dot = fmaf(a4[0], qv[d4*4+0], dot);
            dot = fmaf(a4[1], qv[d4*4+1], dot);
            dot = fmaf(a4[2], qv[d4*4+2], dot);
            dot = fmaf(a4[3], qv[d4*4+3], dot);
        }
        dot += __shfl_xor(dot, 1);
        dot += __shfl_xor(dot, 2);
        const float e = __expf(fmaf(0.125f, dot, b2[a]));
        den += e;
        const float* vp = av_s + a*64 + d0;
#pragma unroll
        for (int d4 = 0; d4 < 4; ++d4) {
            const f32x4 v4 = *(const f32x4*)(vp + d4*4);
            acc[d4*4+0] = fmaf(e, v4[0], acc[d4*4+0]);
            acc[d4*4+1] = fmaf(e, v4[1], acc[d4*4+1]);
            acc[d4*4+2] = fmaf(e, v4[2], acc[d4*4+2]);
            acc[d4*4+3] = fmaf(e, v4[3], acc[d4*4+3]);
        }
    }
    const float inv = 1.0f / den;

    float o[16];
#pragma unroll
    for (int i = 0; i < 16; ++i) o[i] = acc[i]*inv + dwcb_s[d0 + i];
    const int y = jj >> 5, x = jj & 31;
#pragma unroll
    for (int dy = 0; dy < 3; ++dy) {
        const int yy = y + dy - 1;
        if (yy < 0 || yy > 31) continue;
#pragma unroll
        for (int dx = 0; dx < 3; ++dx) {
            const int xx = x + dx - 1;
            if (xx < 0 || xx > 31) continue;
            const unsigned short* vp =
                qkv + (size_t)(b*1024 + yy*32 + xx)*1536 + 1024 + h*64 + d0;
#pragma unroll
            for (int i4 = 0; i4 < 4; ++i4) {
                const u16x4 v4 = *(const u16x4*)(vp + i4*4);
#pragma unroll
                for (int i = 0; i < 4; ++i)
                    o[i4*4+i] = fmaf(dwcw_s[(d0 + i4*4 + i)*9 + dy*3 + dx],
                                     bf2f(v4[i]), o[i4*4+i]);
            }
        }
    }
    unsigned short* op = out_pre + (size_t)(b*1024 + jj)*512 + h*64 + d0;
#pragma unroll
    for (int i4 = 0; i4 < 4; ++i4) {
        u16x4 w;
        w[0]=f2bf(o[i4*4+0]); w[1]=f2bf(o[i4*4+1]);
        w[2]=f2bf(o[i4*4+2]); w[3]=f2bf(o[i4*4+3]);
        *(u16x4*)(op + i4*4) = w;
    }
}

// ---------------------------------------------------------------------------
extern "C" void kernel_launch(void* const* d_in, const int* in_sizes, int n_in,
                              void* d_out, int out_size, void* d_ws, size_t ws_size,
                              hipStream_t stream) {
    (void)in_sizes; (void)n_in; (void)out_size; (void)ws_size;
    const float* x       = (const float*)d_in[0];
    const float* context = (const float*)d_in[1];
    const float* Wq      = (const float*)d_in[2];
    const float* Wkv     = (const float*)d_in[3];
    const float* conv_w  = (const float*)d_in[4];
    const float* conv_b  = (const float*)d_in[5];
    const float* dwc_w   = (const float*)d_in[6];
    const float* dwc_b   = (const float*)d_in[7];
    const float* proj_w  = (const float*)d_in[8];
    const float* proj_b  = (const float*)d_in[9];
    const float* an_bias = (const float*)d_in[10];
    const float* na_bias = (const float*)d_in[11];
    const float* ah_bias = (const float*)d_in[12];
    const float* aw_bias = (const float*)d_in[13];
    const float* ha_bias = (const float*)d_in[14];
    const float* wa_bias = (const float*)d_in[15];

    char* ws = (char*)d_ws;
    size_t off = 0;
    auto alloc = [&](size_t bytes) -> char* {
        char* p = ws + off; off += (bytes + 255) & ~(size_t)255; return p;
    };
    unsigned short* xb     = (unsigned short*)alloc((size_t)16777216 * 2); // 33.5 MB
    unsigned short* qkv    = (unsigned short*)alloc((size_t)50331648 * 2);
    unsigned short* wqkvt  = (unsigned short*)alloc((size_t)786432  * 2);
    unsigned short* projwt = (unsigned short*)alloc((size_t)262144  * 2);
    unsigned short* convwb = (unsigned short*)alloc((size_t)3538944 * 2);
    float*          pooled = (float*)alloc((size_t)1204224 * 4);
    unsigned short* i2c    = (unsigned short*)alloc((size_t)1664*6912*2);  // 23 MB
    float*          at_buf = (float*)alloc((size_t)802816 * 4);
    float*          bias1  = (float*)alloc((size_t)401408 * 4);
    float*          bias2  = (float*)alloc((size_t)401408 * 4);
    float*          agentv = (float*)alloc((size_t)802816 * 4);
    // Aliases (stream-order safe):
    //  - conv split-K partials (28.9 MB) alias xb (dead after qkv GEMM).
    //  - agent partials pn (16.8 MB) + pd (0.26 MB) alias i2c (dead after
    //    the conv GEMM).
    float*          part_conv = (float*)xb;
    float*          pn        = (float*)i2c;
    float*          pd        = pn + (size_t)256*4*64*64;
    unsigned short* outpre    = xb;   // written by qattn_fused (after convred)

    cvt_f32_bf16_kernel<<<16384, 256, 0, stream>>>(x, xb);
    cvt_f32_bf16_kernel<<<3456, 256, 0, stream>>>(conv_w, convwb);
    build_wqkvt_kernel<<<3072, 256, 0, stream>>>(Wq, Wkv, wqkvt);
    build_projwt_kernel<<<1024, 256, 0, stream>>>(proj_w, projwt);
    bias_prep_kernel<<<3136, 256, 0, stream>>>(an_bias, na_bias, ah_bias, aw_bias,
                                               ha_bias, wa_bias, bias1, bias2);
    // qkv = x @ [Wq|Wkv]  (M=32768, N=1536, K=512) -> bf16
    gemm_nt<1><<<dim3(12, 256), 256, 0, stream>>>(xb, wqkvt, qkv, nullptr, 512, 1536, 512);
    pool_kernel<<<4704, 256, 0, stream>>>(qkv, context, pooled);
    im2col_kernel<<<42336, 256, 0, stream>>>(pooled, i2c);
    // conv as split-K GEMM (M=1568 pad 1664, N=512, K=6912, 9 slices of 768)
    gemm_nt<3><<<dim3(4, 13, 9), 256, 0, stream>>>(i2c, convwb, part_conv, nullptr, 6912, 512, 768);
    convred_kernel<<<784, 256, 0, stream>>>(part_conv, conv_b, at_buf);
    // MFMA agent attention, 4 j-slices + combine
    agent_attn_mfma_kernel<<<dim3(256, 4), 256, 0, stream>>>(qkv, at_buf, bias1, pn, pd);
    agent_combine_kernel<<<3136, 256, 0, stream>>>(pn, pd, agentv);
    qattn_fused_kernel<<<dim3(256, 16), 256, 0, stream>>>(qkv, at_buf, agentv, bias2,
                                                          dwc_w, dwc_b, outpre);
    // final: out_pre @ proj_w + proj_b  (M=32768, N=512, K=512) -> f32 d_out
    gemm_nt<0><<<dim3(4, 256), 256, 0, stream>>>(outpre, projwt, d_out, proj_b, 512, 512, 512);
}

// Round 6
// 492.348 us; speedup vs baseline: 1.8413x; 1.1027x over previous
//
#include <hip/hip_runtime.h>
#include <stdint.h>

// ---------------------------------------------------------------------------
// Problem constants (fixed by setup_inputs)
// b=32, n=1024, dim=512, ic=512, cc=256, nh=8, ag=49, hd=64, H=W=c_H=c_W=32
// ---------------------------------------------------------------------------

typedef __attribute__((ext_vector_type(8)))  short          bf16x8;
typedef __attribute__((ext_vector_type(4)))  float          f32x4;
typedef __attribute__((ext_vector_type(4)))  unsigned short u16x4;

__device__ __forceinline__ float bf2f(unsigned short u) {
    union { unsigned int i; float f; } x; x.i = ((unsigned int)u) << 16; return x.f;
}
__device__ __forceinline__ unsigned short f2bf(float f) {
    union { float f; unsigned int i; } x; x.f = f;
    unsigned int i = x.i;
    i += 0x7FFFu + ((i >> 16) & 1u);   // RNE
    return (unsigned short)(i >> 16);
}

// ---------------------------------------------------------------------------
// Elementwise converters
// ---------------------------------------------------------------------------
__global__ void cvt_f32_bf16_kernel(const float* __restrict__ src,
                                    unsigned short* __restrict__ dst) {
    const int i = (blockIdx.x * 256 + threadIdx.x) * 4;
    const f32x4 v = *(const f32x4*)(src + i);
    u16x4 o; o[0]=f2bf(v[0]); o[1]=f2bf(v[1]); o[2]=f2bf(v[2]); o[3]=f2bf(v[3]);
    *(u16x4*)(dst + i) = o;
}

// Wqkv_t[nn][kk] (bf16, N=1536, K=512) from Wq (512,512) and Wkv (512,1024)
__global__ void build_wqkvt_kernel(const float* __restrict__ Wq,
                                   const float* __restrict__ Wkv,
                                   unsigned short* __restrict__ out) {
    const int idx = blockIdx.x * 256 + threadIdx.x;   // = nn*512 + kk
    if (idx >= 1536*512) return;
    const int nn = idx >> 9, kk = idx & 511;
    float v = (nn < 512) ? Wq[kk*512 + nn] : Wkv[kk*1024 + (nn - 512)];
    out[idx] = f2bf(v);
}

__global__ void build_projwt_kernel(const float* __restrict__ W,
                                    unsigned short* __restrict__ out) {
    const int idx = blockIdx.x * 256 + threadIdx.x;   // = nn*512 + kk
    if (idx >= 512*512) return;
    const int nn = idx >> 9, kk = idx & 511;
    out[idx] = f2bf(W[kk*512 + nn]);
}

// ---------------------------------------------------------------------------
// Bias precompute (bilinear 7->32, clamp edges == jax renormalized triangle)
// ---------------------------------------------------------------------------
__device__ __forceinline__ void bilin_coef(int i, int& i0, int& i1, float& f) {
    float pos = (i + 0.5f) * (7.0f / 32.0f) - 0.5f;
    float fl = floorf(pos);
    i0 = (int)fl; f = pos - fl;
    if (i0 < 0)       { i0 = 0; i1 = 0; f = 0.f; }
    else if (i0 >= 6) { i0 = 6; i1 = 6; f = 0.f; }
    else              { i1 = i0 + 1; }
}
__device__ __forceinline__ float bilin7(const float* __restrict__ s, int y, int x) {
    int y0,y1,x0,x1; float fy,fx;
    bilin_coef(y, y0, y1, fy); bilin_coef(x, x0, x1, fx);
    return (1.f-fy)*((1.f-fx)*s[y0*7+x0] + fx*s[y0*7+x1])
         +      fy *((1.f-fx)*s[y1*7+x0] + fx*s[y1*7+x1]);
}

__global__ void bias_prep_kernel(const float* __restrict__ an, const float* __restrict__ na,
                                 const float* __restrict__ ah, const float* __restrict__ aw,
                                 const float* __restrict__ ha, const float* __restrict__ wa,
                                 float* __restrict__ bias1, float* __restrict__ bias2) {
    int idx = blockIdx.x * 256 + threadIdx.x;
    if (idx < 8*49*1024) {
        const int nn = idx & 1023;
        const int a  = (idx >> 10) % 49;
        const int h  = idx / (49*1024);
        const int y = nn >> 5, x = nn & 31;
        float v = bilin7(an + (h*49 + a)*49, y, x)
                + ah[(h*49 + a)*32 + y] + aw[(h*49 + a)*32 + x];
        bias1[idx] = v;
    } else {
        idx -= 8*49*1024;
        if (idx >= 8*1024*49) return;
        const int a  = idx % 49;
        const int nn = (idx / 49) & 1023;
        const int h  = idx / (49*1024);
        const int y = nn >> 5, x = nn & 31;
        float v = bilin7(na + (h*49 + a)*49, y, x)
                + ha[h*1568 + y*49 + a] + wa[h*1568 + x*49 + a];
        bias2[idx] = v;
    }
}

// ---------------------------------------------------------------------------
// Adaptive avg-pool 32x32 -> 7x7 ; pooled flat layout per batch: a*768 + c
// ---------------------------------------------------------------------------
__global__ void pool_kernel(const unsigned short* __restrict__ qkv,
                            const float* __restrict__ context,
                            float* __restrict__ pooled) {
    const int idx = blockIdx.x * 256 + threadIdx.x;   // b*37632 + a*768 + c
    if (idx >= 32*49*768) return;
    const int c = idx % 768;
    const int a = (idx / 768) % 49;
    const int b = idx / (768*49);
    const int p = a / 7, q = a % 7;
    const int ys = p*32/7, ye = (p*32 + 38)/7;
    const int xs = q*32/7, xe = (q*32 + 38)/7;
    float s = 0.f;
    if (c < 512) {
        for (int y = ys; y < ye; ++y)
            for (int x = xs; x < xe; ++x)
                s += bf2f(qkv[(size_t)(b*1024 + y*32 + x)*1536 + c]);
    } else {
        for (int y = ys; y < ye; ++y)
            for (int x = xs; x < xe; ++x)
                s += context[(size_t)(b*1024 + y*32 + x)*256 + (c - 512)];
    }
    pooled[idx] = s / (float)((ye - ys)*(xe - xs));
}

// im2col: out[(b*49 + p*7+q)*6912 + ci*9 + dy*3 + dx]
__global__ void im2col_kernel(const float* __restrict__ pooled,
                              unsigned short* __restrict__ i2c) {
    const int idx = blockIdx.x * 256 + threadIdx.x;
    if (idx >= 1568*6912) return;
    const int kk = idx % 6912;
    const int m  = idx / 6912;
    const int b = m / 49, spq = m % 49;
    const int p = spq / 7, q = spq % 7;
    const int ci = kk / 9, r = kk % 9;
    const int dy = r / 3, dx = r % 3;
    const int yy = p + dy - 1, xx = q + dx - 1;
    float v = 0.f;
    if (yy >= 0 && yy < 7 && xx >= 0 && xx < 7)
        v = pooled[b*37632 + ci*49 + yy*7 + xx];
    i2c[idx] = f2bf(v);
}

// ---------------------------------------------------------------------------
// NT bf16 MFMA GEMM (m97 structure) with split-K support.
// MODE 0: f32 C row-major + bias (proj)   MODE 1: bf16 C row-major (qkv)
// MODE 3: f32 partial tile to part[(z*1568 + m)*512 + n], mask m<1568 (conv)
// ---------------------------------------------------------------------------
template <int MODE>
__launch_bounds__(256)
__global__ void gemm_nt(const unsigned short* __restrict__ A,
                        const unsigned short* __restrict__ Bt,
                        void* __restrict__ C,
                        const float* __restrict__ bias,
                        int K, int ldc, int kspan) {
    __shared__ unsigned short As[128*64];
    __shared__ unsigned short Bs[128*64];
    const int tid  = threadIdx.x;
    const int wid  = tid >> 6;
    const int lane = tid & 63;
    const int m0 = blockIdx.y * 128;
    const int n0 = blockIdx.x * 128;
    const int wm = (wid >> 1) * 64;
    const int wn = (wid & 1) * 64;
    const int lrow = lane & 15;
    const int quad = lane >> 4;
    const int srow = lane >> 3;
    const int scol = ((lane & 7) ^ srow) * 8;

    f32x4 acc[4][4];
#pragma unroll
    for (int i = 0; i < 4; ++i)
#pragma unroll
        for (int j = 0; j < 4; ++j) acc[i][j] = (f32x4){0.f,0.f,0.f,0.f};

    const int kz0 = blockIdx.z * kspan;
    const int kz1 = min(K, kz0 + kspan);
    for (int k0 = kz0; k0 < kz1; k0 += 64) {
        __syncthreads();
#pragma unroll
        for (int i = 0; i < 4; ++i) {
            const int chunk = wid*4 + i;
            const int row = chunk*8 + srow;
            __builtin_amdgcn_global_load_lds(
                (const __attribute__((address_space(1))) void*)(A + (size_t)(m0 + row)*K + k0 + scol),
                (__attribute__((address_space(3))) void*)(As + chunk*512), 16, 0, 0);
            __builtin_amdgcn_global_load_lds(
                (const __attribute__((address_space(1))) void*)(Bt + (size_t)(n0 + row)*K + k0 + scol),
                (__attribute__((address_space(3))) void*)(Bs + chunk*512), 16, 0, 0);
        }
        __syncthreads();
#pragma unroll
        for (int kk = 0; kk < 2; ++kk) {
            bf16x8 af[4], bfr[4];
#pragma unroll
            for (int mt = 0; mt < 4; ++mt) {
                const int row = wm + mt*16 + lrow;
                const int u = (kk*4 + quad) ^ (row & 7);
                af[mt] = *(const bf16x8*)(As + row*64 + u*8);
            }
#pragma unroll
            for (int nt = 0; nt < 4; ++nt) {
                const int row = wn + nt*16 + lrow;
                const int u = (kk*4 + quad) ^ (row & 7);
                bfr[nt] = *(const bf16x8*)(Bs + row*64 + u*8);
            }
#pragma unroll
            for (int mt = 0; mt < 4; ++mt)
#pragma unroll
                for (int nt = 0; nt < 4; ++nt)
                    acc[mt][nt] = __builtin_amdgcn_mfma_f32_16x16x32_bf16(
                        af[mt], bfr[nt], acc[mt][nt], 0, 0, 0);
        }
    }
#pragma unroll
    for (int mt = 0; mt < 4; ++mt) {
#pragma unroll
        for (int nt = 0; nt < 4; ++nt) {
#pragma unroll
            for (int r = 0; r < 4; ++r) {
                const int m = m0 + wm + mt*16 + quad*4 + r;
                const int n = n0 + wn + nt*16 + lrow;
                const float v = acc[mt][nt][r];
                if (MODE == 0) {
                    ((float*)C)[(size_t)m*ldc + n] = v + bias[n];
                } else if (MODE == 1) {
                    ((unsigned short*)C)[(size_t)m*ldc + n] = f2bf(v);
                } else {
                    if (m < 1568)
                        ((float*)C)[((size_t)blockIdx.z*1568 + m)*512 + n] = v;
                }
            }
        }
    }
}

// Sum 9 split-K partials, add conv bias, emit bf16 a_t in row-contiguous
// channel layout: at_bf[(b*49 + a)*512 + ch]  (== raw-reshape scramble view).
__global__ void convred_kernel(const float* __restrict__ part,
                               const float* __restrict__ bias,
                               unsigned short* __restrict__ at_bf) {
    const int idx = blockIdx.x * 256 + threadIdx.x;   // over 1568*128
    if (idx >= 1568*128) return;
    const int m  = idx >> 7;
    const int n4 = (idx & 127) * 4;
    f32x4 s = *(const f32x4*)&part[(size_t)m*512 + n4];
#pragma unroll
    for (int kz = 1; kz < 9; ++kz) {
        const f32x4 p = *(const f32x4*)&part[((size_t)kz*1568 + m)*512 + n4];
        s[0]+=p[0]; s[1]+=p[1]; s[2]+=p[2]; s[3]+=p[3];
    }
    u16x4 o;
    o[0] = f2bf(s[0] + bias[n4+0]);
    o[1] = f2bf(s[1] + bias[n4+1]);
    o[2] = f2bf(s[2] + bias[n4+2]);
    o[3] = f2bf(s[3] + bias[n4+3]);
    *(u16x4*)&at_bf[(size_t)m*512 + n4] = o;
}

// ---------------------------------------------------------------------------
// MFMA agent attention (verified round-5 structure; staging now from bf16
// at_bf). Grid (256 bh, 4 slices), 256 thr (4 waves), wave = 64-j chunk.
// ---------------------------------------------------------------------------
__launch_bounds__(256)
__global__ void agent_attn_mfma_kernel(const unsigned short* __restrict__ qkv,
                                       const unsigned short* __restrict__ at_bf,
                                       const float* __restrict__ bias1,
                                       float* __restrict__ pn,
                                       float* __restrict__ pd) {
    const int bh = blockIdx.x;
    const int b = bh >> 3, h = bh & 7;
    const int sl = blockIdx.y;
    __shared__ unsigned short at_s[64*72];              // [a][d] pad 72
    __shared__ __align__(16) unsigned char smem[4*64*72*2 + 4*64*64*2]; // 69632 B
    unsigned short* P_s = (unsigned short*)smem;        // [4][64*72] bf16
    unsigned short* V_s = (unsigned short*)(smem + 36864); // [4][64*64] bf16
    float* red  = (float*)smem;                         // [4][64*64] f32 (65536 B)
    float* dred = (float*)(smem + 65536);               // [4][64] f32
    const int tid  = threadIdx.x;
    const int wid  = tid >> 6, lane = tid & 63;
    const int l15  = lane & 15, quad = lane >> 4;
    const int j0   = sl*256 + wid*64;

    for (int i = tid; i < 64*72; i += 256) at_s[i] = 0;
    __syncthreads();
    // stage a_t bf16 [a][d] (u16x4 copies, coalesced)
    for (int i = tid; i < 49*16; i += 256) {
        const int a = i >> 4, dq = (i & 15) * 4;
        *(u16x4*)&at_s[a*72 + dq] = *(const u16x4*)&at_bf[(size_t)(b*49 + a)*512 + h*64 + dq];
    }
    // stage V rows j0..j0+63 -> V_s[wid] via global_load_lds (16B/lane)
#pragma unroll
    for (int i = 0; i < 8; ++i) {
        __builtin_amdgcn_global_load_lds(
            (const __attribute__((address_space(1))) void*)
                (qkv + (size_t)(b*1024 + j0 + i*8 + (lane>>3))*1536 + 1024 + h*64 + (lane&7)*8),
            (__attribute__((address_space(3))) void*)(V_s + wid*4096 + i*512), 16, 0, 0);
    }
    // K B-frags straight from global: n=j (lane&15), k=d contiguous
    bf16x8 kfr[4][2];
#pragma unroll
    for (int nt = 0; nt < 4; ++nt)
#pragma unroll
        for (int kf = 0; kf < 2; ++kf)
            kfr[nt][kf] = *(const bf16x8*)
                (qkv + (size_t)(b*1024 + j0 + nt*16 + l15)*1536 + 512 + h*64 + kf*32 + quad*8);
    __syncthreads();   // at_s ready; vmcnt drained -> V_s complete

    bf16x8 af[4][2];
#pragma unroll
    for (int mt = 0; mt < 4; ++mt)
#pragma unroll
        for (int kf = 0; kf < 2; ++kf)
            af[mt][kf] = *(const bf16x8*)(at_s + (mt*16 + l15)*72 + kf*32 + quad*8);

    f32x4 acc[4][4];
#pragma unroll
    for (int i = 0; i < 4; ++i)
#pragma unroll
        for (int j = 0; j < 4; ++j) acc[i][j] = (f32x4){0.f,0.f,0.f,0.f};
#pragma unroll
    for (int kf = 0; kf < 2; ++kf)
#pragma unroll
        for (int mt = 0; mt < 4; ++mt)
#pragma unroll
            for (int nt = 0; nt < 4; ++nt)
                acc[mt][nt] = __builtin_amdgcn_mfma_f32_16x16x32_bf16(
                    af[mt][kf], kfr[nt][kf], acc[mt][nt], 0, 0, 0);

    // bias + exp (fp32), P -> LDS, den partials
    float denp[4][4];
#pragma unroll
    for (int mt = 0; mt < 4; ++mt)
#pragma unroll
        for (int r = 0; r < 4; ++r) denp[mt][r] = 0.f;
#pragma unroll
    for (int mt = 0; mt < 4; ++mt) {
#pragma unroll
        for (int nt = 0; nt < 4; ++nt) {
#pragma unroll
            for (int r = 0; r < 4; ++r) {
                const int a  = mt*16 + quad*4 + r;
                const int ab = (a < 49) ? a : 48;
                const int jj = j0 + nt*16 + l15;
                const float e = __expf(fmaf(0.125f, acc[mt][nt][r],
                                            bias1[(h*49 + ab)*1024 + jj]));
                denp[mt][r] += e;
                P_s[wid*4608 + a*72 + nt*16 + l15] = f2bf(e);
            }
        }
    }
    __syncthreads();   // P_s visible

    // PV: out^T[d][a] = V^T @ P^T  (each wave: its own 64-j chunk)
    f32x4 out[4][4];
#pragma unroll
    for (int i = 0; i < 4; ++i)
#pragma unroll
        for (int j = 0; j < 4; ++j) out[i][j] = (f32x4){0.f,0.f,0.f,0.f};
#pragma unroll
    for (int kf = 0; kf < 2; ++kf) {
        bf16x8 va[4];
#pragma unroll
        for (int mt = 0; mt < 4; ++mt) {
            union { bf16x8 v; unsigned short s[8]; } u;
#pragma unroll
            for (int t = 0; t < 8; ++t)
                u.s[t] = V_s[wid*4096 + (kf*32 + quad*8 + t)*64 + mt*16 + l15];
            va[mt] = u.v;
        }
#pragma unroll
        for (int nt = 0; nt < 4; ++nt) {
            const bf16x8 pb = *(const bf16x8*)(P_s + wid*4608 + (nt*16 + l15)*72 + kf*32 + quad*8);
#pragma unroll
            for (int mt = 0; mt < 4; ++mt)
                out[mt][nt] = __builtin_amdgcn_mfma_f32_16x16x32_bf16(
                    va[mt], pb, out[mt][nt], 0, 0, 0);
        }
    }

    // den: reduce over the 16 j-column lanes (within quad group)
#pragma unroll
    for (int mt = 0; mt < 4; ++mt) {
#pragma unroll
        for (int r = 0; r < 4; ++r) {
            float v = denp[mt][r];
            v += __shfl_xor(v, 1);
            v += __shfl_xor(v, 2);
            v += __shfl_xor(v, 4);
            v += __shfl_xor(v, 8);
            denp[mt][r] = v;
        }
    }

    // ---- in-block cross-wave reduction ----
    __syncthreads();   // all waves done reading P_s/V_s; safe to re-carve
#pragma unroll
    for (int nt = 0; nt < 4; ++nt) {
        const int a = nt*16 + l15;
#pragma unroll
        for (int mt = 0; mt < 4; ++mt)
            *(f32x4*)&red[wid*4096 + a*64 + mt*16 + quad*4] = out[mt][nt];
    }
    if (l15 == 0) {
#pragma unroll
        for (int mt = 0; mt < 4; ++mt)
#pragma unroll
            for (int r = 0; r < 4; ++r)
                dred[wid*64 + mt*16 + quad*4 + r] = denp[mt][r];
    }
    __syncthreads();
    for (int i = tid; i < 4096; i += 256) {
        const float s = red[i] + red[4096 + i] + red[8192 + i] + red[12288 + i];
        pn[((size_t)bh*4 + sl)*4096 + i] = s;   // i = a*64 + d
    }
    if (tid < 64) {
        const float s = dred[tid] + dred[64 + tid] + dred[128 + tid] + dred[192 + tid];
        pd[((size_t)bh*4 + sl)*64 + tid] = s;
    }
}

// Combine 4 j-slice partials; emit bf16 agent_v TRANSPOSED [bh][d][a-pad-64],
// zero for a>=49 (exact padding for the PV K-dim in qattn_mfma).
__global__ void agent_combine_kernel(const float* __restrict__ pn,
                                     const float* __restrict__ pd,
                                     unsigned short* __restrict__ avT) {
    const int idx = blockIdx.x * 256 + threadIdx.x;   // < 256*4096
    if (idx >= 256*4096) return;
    const int bh = idx >> 12;
    const int i  = idx & 4095;        // a*64 + d  (coalesced pn reads)
    const int a = i >> 6, d = i & 63;
    float num = 0.f, den = 0.f;
#pragma unroll
    for (int s = 0; s < 4; ++s) {
        num += pn[(((size_t)bh*4 + s)*64 + a)*64 + d];
        den += pd[((size_t)bh*4 + s)*64 + a];
    }
    avT[(size_t)bh*4096 + d*64 + a] = (a < 49) ? f2bf(num / den) : (unsigned short)0;
}

// ---------------------------------------------------------------------------
// MFMA q-attention + fused depthwise conv.
// Grid (256 bh, 4 token-tiles of 256), 256 thr (4 waves, 64 tokens each).
// Scores S[j][a] = Q @ a_t^T (A=Q global frags, B=at_bf global frags);
// exp+bias fp32; den via shfl over the 16 a-lanes; P normalized -> bf16 LDS;
// PV with B=avT (pre-transposed, zero-padded) -> final out in C-regs;
// LDS transpose (stride-68 f32) -> round-5 dwc mapping -> bf16 out_pre.
// ---------------------------------------------------------------------------
__launch_bounds__(256)
__global__ void qattn_mfma_kernel(const unsigned short* __restrict__ qkv,
                                  const unsigned short* __restrict__ at_bf,
                                  const unsigned short* __restrict__ avT,
                                  const float* __restrict__ bias2,
                                  const float* __restrict__ dwc_w,
                                  const float* __restrict__ dwc_b,
                                  unsigned short* __restrict__ out_pre) {
    const int bh = blockIdx.x;
    const int b = bh >> 3, h = bh & 7;
    const int tq = blockIdx.y;
    __shared__ __align__(16) unsigned char smem[69632];
    unsigned short* P_s = (unsigned short*)smem;   // [4][64*72] bf16 (phase A)
    float* out_s = (float*)smem;                   // [256][68] f32  (phase B)
    __shared__ float dwcw_s[64*9];
    __shared__ float dwcb_s[64];
    const int tid = threadIdx.x;
    const int wid = tid >> 6, lane = tid & 63;
    const int l15 = lane & 15, quad = lane >> 4;
    const int j0  = tq*256 + wid*64;

    for (int i = tid; i < 64*9; i += 256) dwcw_s[i] = dwc_w[h*576 + i];
    if (tid < 64) dwcb_s[tid] = dwc_b[h*64 + tid];

    // Q A-frags from global: m=j (l15 rows), k=d
    bf16x8 qa[4][2];
#pragma unroll
    for (int mt = 0; mt < 4; ++mt)
#pragma unroll
        for (int kf = 0; kf < 2; ++kf)
            qa[mt][kf] = *(const bf16x8*)
                (qkv + (size_t)(b*1024 + j0 + mt*16 + l15)*1536 + h*64 + kf*32 + quad*8);
    // a_t B-frags from global: n=a (l15 rows, clamp >=49 — masked in exp), k=d
    bf16x8 ab[4][2];
#pragma unroll
    for (int nt = 0; nt < 4; ++nt) {
        const int a  = nt*16 + l15;
        const int ar = (a < 49) ? a : 48;
#pragma unroll
        for (int kf = 0; kf < 2; ++kf)
            ab[nt][kf] = *(const bf16x8*)
                (at_bf + (size_t)(b*49 + ar)*512 + h*64 + kf*32 + quad*8);
    }

    f32x4 e[4][4];
#pragma unroll
    for (int i = 0; i < 4; ++i)
#pragma unroll
        for (int j = 0; j < 4; ++j) e[i][j] = (f32x4){0.f,0.f,0.f,0.f};
#pragma unroll
    for (int kf = 0; kf < 2; ++kf)
#pragma unroll
        for (int mt = 0; mt < 4; ++mt)
#pragma unroll
            for (int nt = 0; nt < 4; ++nt)
                e[mt][nt] = __builtin_amdgcn_mfma_f32_16x16x32_bf16(
                    qa[mt][kf], ab[nt][kf], e[mt][nt], 0, 0, 0);

    // exp + bias (C-layout: row j = quad*4+r, col a = l15)
    float denp[4][4];
#pragma unroll
    for (int mt = 0; mt < 4; ++mt)
#pragma unroll
        for (int r = 0; r < 4; ++r) denp[mt][r] = 0.f;
#pragma unroll
    for (int mt = 0; mt < 4; ++mt) {
#pragma unroll
        for (int nt = 0; nt < 4; ++nt) {
            const int a = nt*16 + l15;
#pragma unroll
            for (int r = 0; r < 4; ++r) {
                if (a < 49) {
                    const int jj = j0 + mt*16 + quad*4 + r;
                    const float v = __expf(fmaf(0.125f, e[mt][nt][r],
                                                bias2[((size_t)h*1024 + jj)*49 + a]));
                    e[mt][nt][r] = v;
                    denp[mt][r] += v;
                } else {
                    e[mt][nt][r] = 0.f;
                }
            }
        }
    }
    // den across the 16 a-lanes; normalize P before bf16 quantization
#pragma unroll
    for (int mt = 0; mt < 4; ++mt) {
#pragma unroll
        for (int r = 0; r < 4; ++r) {
            float v = denp[mt][r];
            v += __shfl_xor(v, 1);
            v += __shfl_xor(v, 2);
            v += __shfl_xor(v, 4);
            v += __shfl_xor(v, 8);
            denp[mt][r] = 1.0f / v;
        }
    }
#pragma unroll
    for (int mt = 0; mt < 4; ++mt)
#pragma unroll
        for (int nt = 0; nt < 4; ++nt)
#pragma unroll
            for (int r = 0; r < 4; ++r)
                P_s[wid*4608 + (mt*16 + quad*4 + r)*72 + nt*16 + l15] =
                    f2bf(e[mt][nt][r] * denp[mt][r]);

    // PV: out[j][d] = P @ avT^T   (A=P rows from LDS, B=avT rows from global)
    bf16x8 bv[4][2];
#pragma unroll
    for (int nt = 0; nt < 4; ++nt)
#pragma unroll
        for (int kf = 0; kf < 2; ++kf)
            bv[nt][kf] = *(const bf16x8*)
                (avT + (size_t)bh*4096 + (nt*16 + l15)*64 + kf*32 + quad*8);
    f32x4 out[4][4];
#pragma unroll
    for (int i = 0; i < 4; ++i)
#pragma unroll
        for (int j = 0; j < 4; ++j) out[i][j] = (f32x4){0.f,0.f,0.f,0.f};
#pragma unroll
    for (int kf = 0; kf < 2; ++kf) {
        bf16x8 pa[4];
#pragma unroll
        for (int mt = 0; mt < 4; ++mt)
            pa[mt] = *(const bf16x8*)(P_s + wid*4608 + (mt*16 + l15)*72 + kf*32 + quad*8);
#pragma unroll
        for (int nt = 0; nt < 4; ++nt)
#pragma unroll
            for (int mt = 0; mt < 4; ++mt)
                out[mt][nt] = __builtin_amdgcn_mfma_f32_16x16x32_bf16(
                    pa[mt], bv[nt][kf], out[mt][nt], 0, 0, 0);
    }

    __syncthreads();   // all waves done with P_s; re-carve smem as out_s
#pragma unroll
    for (int mt = 0; mt < 4; ++mt)
#pragma unroll
        for (int nt = 0; nt < 4; ++nt)
#pragma unroll
            for (int r = 0; r < 4; ++r)
                out_s[(wid*64 + mt*16 + quad*4 + r)*68 + nt*16 + l15] = out[mt][nt][r];
    __syncthreads();

    // dwc + store (round-5 proven mapping): thread = (token tt, quarter p)
    const int tt = tid >> 2;
    const int p  = tid & 3;
    const int d0 = p*16;
    for (int it = 0; it < 4; ++it) {
        const int tl = it*64 + tt;
        const int jj = tq*256 + tl;
        float o[16];
#pragma unroll
        for (int i = 0; i < 16; ++i) o[i] = out_s[tl*68 + d0 + i] + dwcb_s[d0 + i];
        const int y = jj >> 5, x = jj & 31;
#pragma unroll
        for (int dy = 0; dy < 3; ++dy) {
            const int yy = y + dy - 1;
            if (yy < 0 || yy > 31) continue;
#pragma unroll
            for (int dx = 0; dx < 3; ++dx) {
                const int xx = x + dx - 1;
                if (xx < 0 || xx > 31) continue;
                const unsigned short* vp =
                    qkv + (size_t)(b*1024 + yy*32 + xx)*1536 + 1024 + h*64 + d0;
#pragma unroll
                for (int i4 = 0; i4 < 4; ++i4) {
                    const u16x4 v4 = *(const u16x4*)(vp + i4*4);
#pragma unroll
                    for (int i = 0; i < 4; ++i)
                        o[i4*4+i] = fmaf(dwcw_s[(d0 + i4*4 + i)*9 + dy*3 + dx],
                                         bf2f(v4[i]), o[i4*4+i]);
                }
            }
        }
        unsigned short* op = out_pre + (size_t)(b*1024 + jj)*512 + h*64 + d0;
#pragma unroll
        for (int i4 = 0; i4 < 4; ++i4) {
            u16x4 w;
            w[0]=f2bf(o[i4*4+0]); w[1]=f2bf(o[i4*4+1]);
            w[2]=f2bf(o[i4*4+2]); w[3]=f2bf(o[i4*4+3]);
            *(u16x4*)(op + i4*4) = w;
        }
    }
}

// ---------------------------------------------------------------------------
extern "C" void kernel_launch(void* const* d_in, const int* in_sizes, int n_in,
                              void* d_out, int out_size, void* d_ws, size_t ws_size,
                              hipStream_t stream) {
    (void)in_sizes; (void)n_in; (void)out_size; (void)ws_size;
    const float* x       = (const float*)d_in[0];
    const float* context = (const float*)d_in[1];
    const float* Wq      = (const float*)d_in[2];
    const float* Wkv     = (const float*)d_in[3];
    const float* conv_w  = (const float*)d_in[4];
    const float* conv_b  = (const float*)d_in[5];
    const float* dwc_w   = (const float*)d_in[6];
    const float* dwc_b   = (const float*)d_in[7];
    const float* proj_w  = (const float*)d_in[8];
    const float* proj_b  = (const float*)d_in[9];
    const float* an_bias = (const float*)d_in[10];
    const float* na_bias = (const float*)d_in[11];
    const float* ah_bias = (const float*)d_in[12];
    const float* aw_bias = (const float*)d_in[13];
    const float* ha_bias = (const float*)d_in[14];
    const float* wa_bias = (const float*)d_in[15];

    char* ws = (char*)d_ws;
    size_t off = 0;
    auto alloc = [&](size_t bytes) -> char* {
        char* p = ws + off; off += (bytes + 255) & ~(size_t)255; return p;
    };
    unsigned short* xb     = (unsigned short*)alloc((size_t)16777216 * 2); // 33.5 MB
    unsigned short* qkv    = (unsigned short*)alloc((size_t)50331648 * 2);
    unsigned short* wqkvt  = (unsigned short*)alloc((size_t)786432  * 2);
    unsigned short* projwt = (unsigned short*)alloc((size_t)262144  * 2);
    unsigned short* convwb = (unsigned short*)alloc((size_t)3538944 * 2);
    float*          pooled = (float*)alloc((size_t)1204224 * 4);
    unsigned short* i2c    = (unsigned short*)alloc((size_t)1664*6912*2);  // 23 MB
    unsigned short* at_bf  = (unsigned short*)alloc((size_t)1568*512*2);   // bf16 a_t
    float*          bias1  = (float*)alloc((size_t)401408 * 4);
    float*          bias2  = (float*)alloc((size_t)401408 * 4);
    unsigned short* avT    = (unsigned short*)alloc((size_t)256*4096*2);   // agent_v^T bf16
    // Aliases (stream-order safe):
    //  - conv split-K partials (28.9 MB) alias xb (dead after qkv GEMM).
    //  - agent partials pn (4.2 MB) + pd (0.26 MB) alias i2c (dead after
    //    the conv GEMM).
    float*          part_conv = (float*)xb;
    float*          pn        = (float*)i2c;
    float*          pd        = pn + (size_t)256*4*64*64;
    unsigned short* outpre    = xb;   // written by qattn_mfma (after convred)

    cvt_f32_bf16_kernel<<<16384, 256, 0, stream>>>(x, xb);
    cvt_f32_bf16_kernel<<<3456, 256, 0, stream>>>(conv_w, convwb);
    build_wqkvt_kernel<<<3072, 256, 0, stream>>>(Wq, Wkv, wqkvt);
    build_projwt_kernel<<<1024, 256, 0, stream>>>(proj_w, projwt);
    bias_prep_kernel<<<3136, 256, 0, stream>>>(an_bias, na_bias, ah_bias, aw_bias,
                                               ha_bias, wa_bias, bias1, bias2);
    // qkv = x @ [Wq|Wkv]  (M=32768, N=1536, K=512) -> bf16
    gemm_nt<1><<<dim3(12, 256), 256, 0, stream>>>(xb, wqkvt, qkv, nullptr, 512, 1536, 512);
    pool_kernel<<<4704, 256, 0, stream>>>(qkv, context, pooled);
    im2col_kernel<<<42336, 256, 0, stream>>>(pooled, i2c);
    // conv as split-K GEMM (M=1568 pad 1664, N=512, K=6912, 9 slices of 768)
    gemm_nt<3><<<dim3(4, 13, 9), 256, 0, stream>>>(i2c, convwb, part_conv, nullptr, 6912, 512, 768);
    convred_kernel<<<784, 256, 0, stream>>>(part_conv, conv_b, at_bf);
    // MFMA agent attention, 4 j-slices + combine (emits avT bf16)
    agent_attn_mfma_kernel<<<dim3(256, 4), 256, 0, stream>>>(qkv, at_bf, bias1, pn, pd);
    agent_combine_kernel<<<4096, 256, 0, stream>>>(pn, pd, avT);
    // MFMA q-attention + fused dwc
    qattn_mfma_kernel<<<dim3(256, 4), 256, 0, stream>>>(qkv, at_bf, avT, bias2,
                                                        dwc_w, dwc_b, outpre);
    // final: out_pre @ proj_w + proj_b  (M=32768, N=512, K=512) -> f32 d_out
    gemm_nt<0><<<dim3(4, 256), 256, 0, stream>>>(outpre, projwt, d_out, proj_b, 512, 512, 512);
}